// Round 2
// baseline (196.712 us; speedup 1.0000x reference)
//
#include <hip/hip_runtime.h>
#include <hip/hip_bf16.h>
#include <math.h>

// Problem constants (kernel_size=7, dilation=2 fixed by the bench's setup_inputs)
#define BB   2
#define HH   56
#define WW   56
#define CIN  64
#define CMID 128

// ws layout in floats
#define SF_OFF 0
#define Q_OFF  802816
#define K_OFF  1605632
#define V_OFF  2408448
#define AS_OFF 3211264   // 56*7 table, pre-scaled by 1/16

// ---------------------------------------------------------------------------
// Kernel 1: 3x3 SAME conv, NCHW input -> BHWC output (+bias)
// grid (4 wtiles, 56 h, 2 b), block 256. Each block: one row segment of 14 w
// positions x all 128 out channels. x patch staged in LDS; weights from L2.
// ---------------------------------------------------------------------------
__global__ __launch_bounds__(256) void conv3x3_kernel(
    const float* __restrict__ x, const float* __restrict__ cw,
    const float* __restrict__ cb, float* __restrict__ sf)
{
    __shared__ float xs[CIN][3][16];
    const int wt = blockIdx.x;   // 0..3
    const int h  = blockIdx.y;
    const int b  = blockIdx.z;
    const int w0 = wt * 14;
    const int tid = threadIdx.x;

    for (int l = tid; l < CIN * 3 * 16; l += 256) {
        int c  = l / 48;
        int r  = l % 48;
        int dh = r / 16;
        int wi = r % 16;
        int y  = h + dh - 1;
        int wg = w0 - 1 + wi;
        float v = 0.f;
        if ((unsigned)y < HH && (unsigned)wg < WW)
            v = x[((b * CIN + c) * HH + y) * WW + wg];
        xs[c][dh][wi] = v;
    }
    __syncthreads();

    const int o     = tid & 127;
    const int half  = tid >> 7;      // 0 or 1
    const int wbase = half * 7;

    float acc[7];
    const float bias = cb[o];
#pragma unroll
    for (int j = 0; j < 7; ++j) acc[j] = bias;

    const float* wro = cw + o * (CIN * 9);
    for (int c = 0; c < CIN; ++c) {
#pragma unroll
        for (int dh = 0; dh < 3; ++dh) {
            const float wv0 = wro[c * 9 + dh * 3 + 0];
            const float wv1 = wro[c * 9 + dh * 3 + 1];
            const float wv2 = wro[c * 9 + dh * 3 + 2];
            float xv[9];
#pragma unroll
            for (int t = 0; t < 9; ++t) xv[t] = xs[c][dh][wbase + t];
#pragma unroll
            for (int j = 0; j < 7; ++j)
                acc[j] += wv0 * xv[j] + wv1 * xv[j + 1] + wv2 * xv[j + 2];
        }
    }
#pragma unroll
    for (int j = 0; j < 7; ++j) {
        int w = w0 + wbase + j;
        sf[((b * HH + h) * WW + w) * CMID + o] = acc[j];
    }
}

// ---------------------------------------------------------------------------
// Kernel 2: PE-dot table A[i][j] = sum_t cos((i - idx(i,j)) * div_t), scaled
// by 1/16. (sin a sin b + cos a cos b = cos(a-b); eh == ew since both dim 64.)
// ---------------------------------------------------------------------------
__global__ void tables_kernel(float* __restrict__ As)
{
    int t = threadIdx.x;
    if (t >= 56 * 7) return;
    int i = t / 7, j = t % 7;
    int r = i & 1, p = i >> 1;
    int start = p - 3;
    if (start < 0) start = 0;
    if (start > 21) start = 21;
    int nidx = r + (start + j) * 2;
    float delta = (float)(i - nidx);
    float acc = 0.f;
    for (int u = 0; u < 32; ++u) {
        float d = expf(-9.210340371976184f * (float)u * 0.03125f); // 10000^(-u/32)
        acc += cosf(delta * d);
    }
    As[t] = acc * 0.0625f;
}

// ---------------------------------------------------------------------------
// Kernel 3: fused QKV projection. sf (6272x128) x 3 weight matrices (128x128).
// q is pre-scaled by 1/16 (softmax scale). grid 392 blocks x 256 thr,
// 16 positions per block staged in LDS.
// ---------------------------------------------------------------------------
__global__ __launch_bounds__(256) void qkv_kernel(
    const float* __restrict__ sf,
    const float* __restrict__ qw, const float* __restrict__ qb,
    const float* __restrict__ kw, const float* __restrict__ kb,
    const float* __restrict__ vw, const float* __restrict__ vb,
    float* __restrict__ qo, float* __restrict__ ko, float* __restrict__ vo)
{
    __shared__ float sfs[16][CMID];
    const int p0  = blockIdx.x * 16;
    const int tid = threadIdx.x;
    for (int l = tid; l < 16 * CMID; l += 256)
        sfs[l >> 7][l & 127] = sf[p0 * CMID + l];
    __syncthreads();

    const int o    = tid & 127;
    const int half = tid >> 7;
    float aq[8], ak[8], av[8];
#pragma unroll
    for (int j = 0; j < 8; ++j) { aq[j] = 0.f; ak[j] = 0.f; av[j] = 0.f; }

    const float* qwr = qw + o * CMID;
    const float* kwr = kw + o * CMID;
    const float* vwr = vw + o * CMID;
    for (int c = 0; c < CMID; ++c) {
        const float wq = qwr[c], wk = kwr[c], wv = vwr[c];
#pragma unroll
        for (int j = 0; j < 8; ++j) {
            const float s = sfs[half * 8 + j][c];
            aq[j] += wq * s;
            ak[j] += wk * s;
            av[j] += wv * s;
        }
    }
    const float bq = qb[o], bk = kb[o], bv = vb[o];
#pragma unroll
    for (int j = 0; j < 8; ++j) {
        const int p = p0 + half * 8 + j;
        qo[p * CMID + o] = (aq[j] + bq) * 0.0625f;  // fold softmax scale
        ko[p * CMID + o] = ak[j] + bk;
        vo[p * CMID + o] = av[j] + bv;
    }
}

// ---------------------------------------------------------------------------
// Kernel 4: neighborhood attention. One wave (64 lanes) per query point.
// Lanes 0..48 each compute one 128-dim QK dot; wave-shuffle softmax;
// PV with 2 channels/lane (coalesced v row reads).
// ---------------------------------------------------------------------------
__global__ __launch_bounds__(256) void attn_kernel(
    const float* __restrict__ q, const float* __restrict__ k,
    const float* __restrict__ v, const float* __restrict__ As,
    float* __restrict__ out)
{
    __shared__ float qs[4][CMID];
    __shared__ float aw[4][64];
    __shared__ int   nb[4][64];
    const int tid  = threadIdx.x;
    const int wv   = tid >> 6;
    const int lane = tid & 63;
    const int g    = blockIdx.x * 4 + wv;   // query index < 6272
    const int b    = g / (HH * WW);
    const int rem  = g % (HH * WW);
    const int h    = rem / WW;
    const int w    = rem % WW;

    { // load q row to LDS (coalesced float2)
        float2 qv = *(const float2*)(q + g * CMID + lane * 2);
        qs[wv][lane * 2]     = qv.x;
        qs[wv][lane * 2 + 1] = qv.y;
    }
    __syncthreads();

    // neighbor for this lane (clamp inactive lanes to a valid index)
    const int n  = lane < 49 ? lane : 48;
    const int u  = n / 7, vvn = n % 7;
    int sh = (h >> 1) - 3; sh = sh < 0 ? 0 : (sh > 21 ? 21 : sh);
    int sw = (w >> 1) - 3; sw = sw < 0 ? 0 : (sw > 21 ? 21 : sw);
    const int ihn = (h & 1) + (sh + u) * 2;
    const int iwn = (w & 1) + (sw + vvn) * 2;
    const int base = ((b * HH + ihn) * WW + iwn) * CMID;

    float acc = 0.f;
    const float* kr = k + base;
#pragma unroll 8
    for (int c = 0; c < CMID; c += 4) {
        float4 kv = *(const float4*)(kr + c);
        float4 qv = *(const float4*)(&qs[wv][c]);   // broadcast
        acc += qv.x * kv.x + qv.y * kv.y + qv.z * kv.z + qv.w * kv.w;
    }
    float logit = acc + As[h * 7 + u] + As[w * 7 + vvn];
    if (lane >= 49) logit = -INFINITY;

    // wave softmax (64-lane butterfly)
    float m = logit;
#pragma unroll
    for (int s = 32; s > 0; s >>= 1)
        m = fmaxf(m, __shfl_xor(m, s, 64));
    const float e = (lane < 49) ? expf(logit - m) : 0.f;
    float ssum = e;
#pragma unroll
    for (int s = 32; s > 0; s >>= 1)
        ssum += __shfl_xor(ssum, s, 64);
    const float a = e / ssum;

    aw[wv][lane] = a;
    nb[wv][lane] = base;
    __syncthreads();

    // PV: 2 channels per lane, coalesced row reads of v
    const int c0 = lane * 2;
    float o0 = 0.f, o1 = 0.f;
    for (int n2 = 0; n2 < 49; ++n2) {
        const float a2 = aw[wv][n2];
        const int   bs = nb[wv][n2];
        float2 vv2 = *(const float2*)(v + bs + c0);
        o0 += a2 * vv2.x;
        o1 += a2 * vv2.y;
    }
    *(float2*)(out + g * CMID + c0) = make_float2(o0, o1);
}

// ---------------------------------------------------------------------------
extern "C" void kernel_launch(void* const* d_in, const int* in_sizes, int n_in,
                              void* d_out, int out_size, void* d_ws, size_t ws_size,
                              hipStream_t stream)
{
    const float* x  = (const float*)d_in[0];
    const float* cw = (const float*)d_in[1];
    const float* cb = (const float*)d_in[2];
    const float* qw = (const float*)d_in[3];
    const float* qb = (const float*)d_in[4];
    const float* kw = (const float*)d_in[5];
    const float* kb = (const float*)d_in[6];
    const float* vw = (const float*)d_in[7];
    const float* vb = (const float*)d_in[8];
    // d_in[9]=kernel_size(7), d_in[10]=dilation(2) — compile-time constants here.

    float* ws  = (float*)d_ws;
    float* sf  = ws + SF_OFF;
    float* qx  = ws + Q_OFF;
    float* kx  = ws + K_OFF;
    float* vx  = ws + V_OFF;
    float* As  = ws + AS_OFF;
    float* out = (float*)d_out;

    hipLaunchKernelGGL(conv3x3_kernel, dim3(4, 56, 2), dim3(256), 0, stream,
                       x, cw, cb, sf);
    hipLaunchKernelGGL(tables_kernel, dim3(1), dim3(448), 0, stream, As);
    hipLaunchKernelGGL(qkv_kernel, dim3(392), dim3(256), 0, stream,
                       sf, qw, qb, kw, kb, vw, vb, qx, kx, vx);
    hipLaunchKernelGGL(attn_kernel, dim3(1568), dim3(256), 0, stream,
                       qx, kx, vx, As, out);
}

// Round 3
// 183.756 us; speedup vs baseline: 1.0705x; 1.0705x over previous
//
#include <hip/hip_runtime.h>
#include <hip/hip_bf16.h>
#include <math.h>

// Problem constants (kernel_size=7, dilation=2 fixed by the bench's setup_inputs)
#define BB   2
#define HH   56
#define WW   56
#define CIN  64
#define CMID 128

// ws layout in floats
#define SF_OFF  0
#define Q_OFF   802816
#define K_OFF   1605632
#define V_OFF   2408448
#define AS_OFF  3211264              // 56*7 table, pre-scaled by 1/16
#define CWT_OFF 3211712              // 576*128 transposed conv weights
#define QWT_OFF (CWT_OFF + 73728)    // 128*128 each
#define KWT_OFF (QWT_OFF + 16384)
#define VWT_OFF (KWT_OFF + 16384)

// ---------------------------------------------------------------------------
// Kernel 0: transpose weights so that the output-channel index is the fastest
// dim (coalesced lane reads in conv/qkv). cw[o][k] -> cwT[k][o], etc.
// ---------------------------------------------------------------------------
__global__ __launch_bounds__(256) void transpose_w_kernel(
    const float* __restrict__ cw, const float* __restrict__ qw,
    const float* __restrict__ kw, const float* __restrict__ vw,
    float* __restrict__ cwT, float* __restrict__ qwT,
    float* __restrict__ kwT, float* __restrict__ vwT)
{
    int idx = blockIdx.x * 256 + threadIdx.x;
    if (idx < 128 * 576) {
        int o = idx / 576, t = idx % 576;
        cwT[t * 128 + o] = cw[idx];
    }
    if (idx < 128 * 128) {
        int o = idx / 128, c = idx % 128;
        qwT[c * 128 + o] = qw[idx];
        kwT[c * 128 + o] = kw[idx];
        vwT[c * 128 + o] = vw[idx];
    }
}

// ---------------------------------------------------------------------------
// Kernel 1: 3x3 SAME conv, NCHW input -> BHWC output (+bias), coalesced
// transposed weights. grid (4 wtiles, 56 h, 2 b), block 256.
// ---------------------------------------------------------------------------
__global__ __launch_bounds__(256) void conv3x3_kernel(
    const float* __restrict__ x, const float* __restrict__ cwT,
    const float* __restrict__ cb, float* __restrict__ sf)
{
    __shared__ float xs[CIN][3][16];
    const int wt = blockIdx.x;   // 0..3
    const int h  = blockIdx.y;
    const int b  = blockIdx.z;
    const int w0 = wt * 14;
    const int tid = threadIdx.x;

    for (int l = tid; l < CIN * 3 * 16; l += 256) {
        int c  = l / 48;
        int r  = l % 48;
        int dh = r / 16;
        int wi = r % 16;
        int y  = h + dh - 1;
        int wg = w0 - 1 + wi;
        float v = 0.f;
        if ((unsigned)y < HH && (unsigned)wg < WW)
            v = x[((b * CIN + c) * HH + y) * WW + wg];
        xs[c][dh][wi] = v;
    }
    __syncthreads();

    const int o     = tid & 127;
    const int half  = tid >> 7;      // 0 or 1
    const int wbase = half * 7;

    float acc[7];
    const float bias = cb[o];
#pragma unroll
    for (int j = 0; j < 7; ++j) acc[j] = bias;

    for (int c = 0; c < CIN; ++c) {
#pragma unroll
        for (int dh = 0; dh < 3; ++dh) {
            // coalesced: lane o reads consecutive addresses
            const float* wp = cwT + (c * 9 + dh * 3) * 128 + o;
            const float wv0 = wp[0];
            const float wv1 = wp[128];
            const float wv2 = wp[256];
            float xv[9];
#pragma unroll
            for (int t = 0; t < 9; ++t) xv[t] = xs[c][dh][wbase + t];  // broadcast
#pragma unroll
            for (int j = 0; j < 7; ++j)
                acc[j] += wv0 * xv[j] + wv1 * xv[j + 1] + wv2 * xv[j + 2];
        }
    }
#pragma unroll
    for (int j = 0; j < 7; ++j) {
        int w = w0 + wbase + j;
        sf[((b * HH + h) * WW + w) * CMID + o] = acc[j];
    }
}

// ---------------------------------------------------------------------------
// Kernel 2: PE-dot table A[i][j] = sum_t cos((i - idx(i,j)) * div_t), scaled
// by 1/16. (sin a sin b + cos a cos b = cos(a-b); eh == ew since both dim 64.)
// ---------------------------------------------------------------------------
__global__ void tables_kernel(float* __restrict__ As)
{
    int t = threadIdx.x;
    if (t >= 56 * 7) return;
    int i = t / 7, j = t % 7;
    int r = i & 1, p = i >> 1;
    int start = p - 3;
    if (start < 0) start = 0;
    if (start > 21) start = 21;
    int nidx = r + (start + j) * 2;
    float delta = (float)(i - nidx);
    float acc = 0.f;
    for (int u = 0; u < 32; ++u) {
        float d = expf(-9.210340371976184f * (float)u * 0.03125f); // 10000^(-u/32)
        acc += cosf(delta * d);
    }
    As[t] = acc * 0.0625f;
}

// ---------------------------------------------------------------------------
// Kernel 3: fused QKV projection with coalesced transposed weights.
// grid 784 blocks x 256 thr, 8 positions per block (4 per thread).
// q pre-scaled by 1/16.
// ---------------------------------------------------------------------------
__global__ __launch_bounds__(256) void qkv_kernel(
    const float* __restrict__ sf,
    const float* __restrict__ qwT, const float* __restrict__ qb,
    const float* __restrict__ kwT, const float* __restrict__ kb,
    const float* __restrict__ vwT, const float* __restrict__ vb,
    float* __restrict__ qo, float* __restrict__ ko, float* __restrict__ vo)
{
    __shared__ float sfs[8][CMID];
    const int p0  = blockIdx.x * 8;
    const int tid = threadIdx.x;
    for (int l = tid; l < 8 * CMID; l += 256)
        sfs[l >> 7][l & 127] = sf[p0 * CMID + l];
    __syncthreads();

    const int o    = tid & 127;
    const int half = tid >> 7;
    float aq[4], ak[4], av[4];
#pragma unroll
    for (int j = 0; j < 4; ++j) { aq[j] = 0.f; ak[j] = 0.f; av[j] = 0.f; }

    for (int c = 0; c < CMID; ++c) {
        const float wq = qwT[c * 128 + o];   // coalesced
        const float wk = kwT[c * 128 + o];
        const float wv = vwT[c * 128 + o];
#pragma unroll
        for (int j = 0; j < 4; ++j) {
            const float s = sfs[half * 4 + j][c];   // broadcast
            aq[j] += wq * s;
            ak[j] += wk * s;
            av[j] += wv * s;
        }
    }
    const float bq = qb[o], bk = kb[o], bv = vb[o];
#pragma unroll
    for (int j = 0; j < 4; ++j) {
        const int p = p0 + half * 4 + j;
        qo[p * CMID + o] = (aq[j] + bq) * 0.0625f;  // fold softmax scale
        ko[p * CMID + o] = ak[j] + bk;
        vo[p * CMID + o] = av[j] + bv;
    }
}

// ---------------------------------------------------------------------------
// Kernel 4: neighborhood attention. One wave (64 lanes) per query point.
// Lanes 0..48 each compute one 128-dim QK dot; wave-shuffle softmax;
// PV with 2 channels/lane (coalesced v row reads).
// ---------------------------------------------------------------------------
__global__ __launch_bounds__(256) void attn_kernel(
    const float* __restrict__ q, const float* __restrict__ k,
    const float* __restrict__ v, const float* __restrict__ As,
    float* __restrict__ out)
{
    __shared__ float qs[4][CMID];
    __shared__ float aw[4][64];
    __shared__ int   nb[4][64];
    const int tid  = threadIdx.x;
    const int wv   = tid >> 6;
    const int lane = tid & 63;
    const int g    = blockIdx.x * 4 + wv;   // query index < 6272
    const int b    = g / (HH * WW);
    const int rem  = g % (HH * WW);
    const int h    = rem / WW;
    const int w    = rem % WW;

    { // load q row to LDS (coalesced float2)
        float2 qv = *(const float2*)(q + g * CMID + lane * 2);
        qs[wv][lane * 2]     = qv.x;
        qs[wv][lane * 2 + 1] = qv.y;
    }
    __syncthreads();

    // neighbor for this lane (clamp inactive lanes to a valid index)
    const int n  = lane < 49 ? lane : 48;
    const int u  = n / 7, vvn = n % 7;
    int sh = (h >> 1) - 3; sh = sh < 0 ? 0 : (sh > 21 ? 21 : sh);
    int sw = (w >> 1) - 3; sw = sw < 0 ? 0 : (sw > 21 ? 21 : sw);
    const int ihn = (h & 1) + (sh + u) * 2;
    const int iwn = (w & 1) + (sw + vvn) * 2;
    const int base = ((b * HH + ihn) * WW + iwn) * CMID;

    float acc = 0.f;
    const float* kr = k + base;
#pragma unroll 8
    for (int c = 0; c < CMID; c += 4) {
        float4 kv = *(const float4*)(kr + c);
        float4 qv = *(const float4*)(&qs[wv][c]);   // broadcast
        acc += qv.x * kv.x + qv.y * kv.y + qv.z * kv.z + qv.w * kv.w;
    }
    float logit = acc + As[h * 7 + u] + As[w * 7 + vvn];
    if (lane >= 49) logit = -INFINITY;

    // wave softmax (64-lane butterfly)
    float m = logit;
#pragma unroll
    for (int s = 32; s > 0; s >>= 1)
        m = fmaxf(m, __shfl_xor(m, s, 64));
    const float e = (lane < 49) ? expf(logit - m) : 0.f;
    float ssum = e;
#pragma unroll
    for (int s = 32; s > 0; s >>= 1)
        ssum += __shfl_xor(ssum, s, 64);
    const float a = e / ssum;

    aw[wv][lane] = a;
    nb[wv][lane] = base;
    __syncthreads();

    // PV: 2 channels per lane, coalesced row reads of v
    const int c0 = lane * 2;
    float o0 = 0.f, o1 = 0.f;
    for (int n2 = 0; n2 < 49; ++n2) {
        const float a2 = aw[wv][n2];
        const int   bs = nb[wv][n2];
        float2 vv2 = *(const float2*)(v + bs + c0);
        o0 += a2 * vv2.x;
        o1 += a2 * vv2.y;
    }
    *(float2*)(out + g * CMID + c0) = make_float2(o0, o1);
}

// ---------------------------------------------------------------------------
extern "C" void kernel_launch(void* const* d_in, const int* in_sizes, int n_in,
                              void* d_out, int out_size, void* d_ws, size_t ws_size,
                              hipStream_t stream)
{
    const float* x  = (const float*)d_in[0];
    const float* cw = (const float*)d_in[1];
    const float* cb = (const float*)d_in[2];
    const float* qw = (const float*)d_in[3];
    const float* qb = (const float*)d_in[4];
    const float* kw = (const float*)d_in[5];
    const float* kb = (const float*)d_in[6];
    const float* vw = (const float*)d_in[7];
    const float* vb = (const float*)d_in[8];
    // d_in[9]=kernel_size(7), d_in[10]=dilation(2) — compile-time constants here.

    float* ws  = (float*)d_ws;
    float* sf  = ws + SF_OFF;
    float* qx  = ws + Q_OFF;
    float* kx  = ws + K_OFF;
    float* vx  = ws + V_OFF;
    float* As  = ws + AS_OFF;
    float* cwT = ws + CWT_OFF;
    float* qwT = ws + QWT_OFF;
    float* kwT = ws + KWT_OFF;
    float* vwT = ws + VWT_OFF;
    float* out = (float*)d_out;

    hipLaunchKernelGGL(transpose_w_kernel, dim3(288), dim3(256), 0, stream,
                       cw, qw, kw, vw, cwT, qwT, kwT, vwT);
    hipLaunchKernelGGL(conv3x3_kernel, dim3(4, 56, 2), dim3(256), 0, stream,
                       x, cwT, cb, sf);
    hipLaunchKernelGGL(tables_kernel, dim3(1), dim3(448), 0, stream, As);
    hipLaunchKernelGGL(qkv_kernel, dim3(784), dim3(256), 0, stream,
                       sf, qwT, qb, kwT, kb, vwT, vb, qx, kx, vx);
    hipLaunchKernelGGL(attn_kernel, dim3(1568), dim3(256), 0, stream,
                       qx, kx, vx, As, out);
}

// Round 4
// 162.877 us; speedup vs baseline: 1.2077x; 1.1282x over previous
//
#include <hip/hip_runtime.h>
#include <hip/hip_bf16.h>
#include <math.h>

// Problem constants (kernel_size=7, dilation=2 fixed by the bench's setup_inputs)
#define BB   2
#define HH   56
#define WW   56
#define CIN  64
#define CMID 128

typedef short bf8_t __attribute__((ext_vector_type(8)));   // 8 x bf16 (4 VGPRs)
typedef float f4_t  __attribute__((ext_vector_type(4)));   // 4 x f32 acc

// ws layout in floats
#define Q_OFF   0
#define K_OFF   802816
#define V_OFF   1605632
#define AS_OFF  2408448              // 56*7 table, pre-scaled by 1/16
#define SFH_OFF 2408840              // sf hi, 802816 bf16 = 401408 float slots
#define SFL_OFF 2810248
#define WFH_OFF 3211656              // conv w hi: 9*128*64 bf16 = 36864 f
#define WFL_OFF 3248520
#define W2H_OFF 3285384              // qkv w hi: 384*128 bf16 = 24576 f
#define W2L_OFF 3309960
// end 3334536 floats = 12.72 MiB

__device__ __forceinline__ unsigned short f2bf(float f) {
    unsigned int u = __builtin_bit_cast(unsigned int, f);
    u += 0x7fffu + ((u >> 16) & 1u);          // RTN-even
    return (unsigned short)(u >> 16);
}
__device__ __forceinline__ float bf2f(unsigned short h) {
    unsigned int u = ((unsigned int)h) << 16;
    return __builtin_bit_cast(float, u);
}

// ---------------------------------------------------------------------------
// Prep: split weights into bf16 hi/lo, fragment-friendly layouts.
// conv: cw[o][c][dh][dw] -> wf[seg=dh*3+dw][o][c]   (c fastest -> B-frag 16B)
// qkv : qw/kw/vw[o][c]   -> wf2[(which*128+o)][c]
// ---------------------------------------------------------------------------
__global__ __launch_bounds__(256) void prep_w(
    const float* __restrict__ cw, const float* __restrict__ qw,
    const float* __restrict__ kw, const float* __restrict__ vw,
    unsigned short* __restrict__ wfh, unsigned short* __restrict__ wfl,
    unsigned short* __restrict__ w2h, unsigned short* __restrict__ w2l)
{
    int idx = blockIdx.x * 256 + threadIdx.x;
    if (idx < 128 * 64 * 9) {
        int o = idx / (64 * 9);
        int rem = idx % (64 * 9);
        int c = rem / 9;
        int seg = rem % 9;
        float wv = cw[idx];                    // idx == (o*64+c)*9+seg
        unsigned short hi = f2bf(wv);
        unsigned short lo = f2bf(wv - bf2f(hi));
        int dst = (seg * 128 + o) * 64 + c;
        wfh[dst] = hi; wfl[dst] = lo;
    }
    if (idx < 128 * 128) {
        float wv = qw[idx];
        unsigned short hi = f2bf(wv);
        w2h[idx] = hi; w2l[idx] = f2bf(wv - bf2f(hi));
        wv = kw[idx];
        hi = f2bf(wv);
        w2h[16384 + idx] = hi; w2l[16384 + idx] = f2bf(wv - bf2f(hi));
        wv = vw[idx];
        hi = f2bf(wv);
        w2h[32768 + idx] = hi; w2l[32768 + idx] = f2bf(wv - bf2f(hi));
    }
}

// ---------------------------------------------------------------------------
// PE-dot table A[i][j] = sum_t cos((i - idx(i,j)) * div_t) / 16.
// ---------------------------------------------------------------------------
__global__ void tables_kernel(float* __restrict__ As)
{
    int t = threadIdx.x;
    if (t >= 56 * 7) return;
    int i = t / 7, j = t % 7;
    int r = i & 1, p = i >> 1;
    int start = p - 3;
    if (start < 0) start = 0;
    if (start > 21) start = 21;
    int nidx = r + (start + j) * 2;
    float delta = (float)(i - nidx);
    float acc = 0.f;
    for (int u = 0; u < 32; ++u) {
        float d = expf(-9.210340371976184f * (float)u * 0.03125f);
        acc += cosf(delta * d);
    }
    As[t] = acc * 0.0625f;
}

// ---------------------------------------------------------------------------
// Conv as 9 accumulated MFMA GEMMs, double-bf16 (hi/lo) precision.
// Block = one (b,h) row: M=64 (56 w + pad), N=128, K=9*64.
// 8 waves = 2(M) x 4(N); per wave 2x2 16x16 frags, 216 MFMA.
// A staged in LDS (XOR-swizzled); B read from global (L2-hot).
// ---------------------------------------------------------------------------
__global__ __launch_bounds__(512) void conv_mfma(
    const float* __restrict__ x,
    const unsigned short* __restrict__ wfh, const unsigned short* __restrict__ wfl,
    const float* __restrict__ cb,
    unsigned short* __restrict__ sfh, unsigned short* __restrict__ sfl)
{
    __shared__ char xsb[2][3 * 66 * 64 * 2];   // [hi/lo][dh][row0..65][c0..63] bf16
    const int h   = blockIdx.x;
    const int b   = blockIdx.y;
    const int tid = threadIdx.x;

    // stage x -> LDS bf16 hi/lo, zero-padded, XOR-swizzled
    for (int idx = tid; idx < 3 * 64 * 66; idx += 512) {
        int dh  = idx / (64 * 66);
        int rem = idx % (64 * 66);
        int c   = rem / 66;
        int row = rem % 66;                    // input col = row-1
        int y   = h + dh - 1;
        int wg  = row - 1;
        float val = 0.f;
        if ((unsigned)y < HH && (unsigned)wg < WW)
            val = x[((b * CIN + c) * HH + y) * WW + wg];
        unsigned short hi = f2bf(val);
        unsigned short lo = f2bf(val - bf2f(hi));
        int byteoff = (((dh * 66 + row) * 64 + c) * 2) ^ ((row & 7) << 4);
        *(unsigned short*)(xsb[0] + byteoff) = hi;
        *(unsigned short*)(xsb[1] + byteoff) = lo;
    }
    __syncthreads();

    const int lane   = tid & 63;
    const int wid    = tid >> 6;
    const int wm     = wid >> 2;       // 0..1
    const int wn     = wid & 3;        // 0..3
    const int lane15 = lane & 15;
    const int lanehi = lane >> 4;

    f4_t acc[2][2] = {};

    for (int seg = 0; seg < 9; ++seg) {
        const int dh = seg / 3, dw = seg % 3;
        const int bbase = (seg * 128) * 64 + lanehi * 8;
#pragma unroll
        for (int kk = 0; kk < 64; kk += 32) {
            bf8_t ah[2], al[2], bh[2], bl[2];
#pragma unroll
            for (int mf = 0; mf < 2; ++mf) {
                int row = wm * 32 + mf * 16 + lane15 + dw;
                int byteoff = (((dh * 66 + row) * 64 + kk + lanehi * 8) * 2)
                              ^ ((row & 7) << 4);
                ah[mf] = *(const bf8_t*)(xsb[0] + byteoff);
                al[mf] = *(const bf8_t*)(xsb[1] + byteoff);
            }
#pragma unroll
            for (int nf = 0; nf < 2; ++nf) {
                int o = wn * 32 + nf * 16 + lane15;
                bh[nf] = *(const bf8_t*)(wfh + bbase + o * 64 + kk);
                bl[nf] = *(const bf8_t*)(wfl + bbase + o * 64 + kk);
            }
#pragma unroll
            for (int mf = 0; mf < 2; ++mf)
#pragma unroll
                for (int nf = 0; nf < 2; ++nf) {
                    acc[mf][nf] = __builtin_amdgcn_mfma_f32_16x16x32_bf16(
                        ah[mf], bh[nf], acc[mf][nf], 0, 0, 0);
                    acc[mf][nf] = __builtin_amdgcn_mfma_f32_16x16x32_bf16(
                        al[mf], bh[nf], acc[mf][nf], 0, 0, 0);
                    acc[mf][nf] = __builtin_amdgcn_mfma_f32_16x16x32_bf16(
                        ah[mf], bl[nf], acc[mf][nf], 0, 0, 0);
                }
        }
    }

    // epilogue: +bias, split hi/lo, store sf (skip pad rows w>=56)
    const int r4 = lanehi * 4;
#pragma unroll
    for (int mf = 0; mf < 2; ++mf) {
        int wr = wm * 32 + mf * 16 + r4;
#pragma unroll
        for (int nf = 0; nf < 2; ++nf) {
            int o = wn * 32 + nf * 16 + lane15;
            float bias = cb[o];
#pragma unroll
            for (int r = 0; r < 4; ++r) {
                int wpos = wr + r;
                if (wpos < 56) {
                    float val = acc[mf][nf][r] + bias;
                    unsigned short hi = f2bf(val);
                    unsigned short lo = f2bf(val - bf2f(hi));
                    int dst = ((b * HH + h) * WW + wpos) * CMID + o;
                    sfh[dst] = hi; sfl[dst] = lo;
                }
            }
        }
    }
}

// ---------------------------------------------------------------------------
// QKV: one GEMM M=6272, N=384 (q|k|v), K=128, double-bf16.
// Block: 64 positions; 8 waves = 2(M) x 4(N); wave tile 32x96 (2x6 frags).
// Epilogue: +bias, q scaled 1/16, fp32 out.
// ---------------------------------------------------------------------------
__global__ __launch_bounds__(512) void qkv_mfma(
    const unsigned short* __restrict__ sfh, const unsigned short* __restrict__ sfl,
    const unsigned short* __restrict__ w2h, const unsigned short* __restrict__ w2l,
    const float* __restrict__ qb, const float* __restrict__ kb,
    const float* __restrict__ vb,
    float* __restrict__ qo, float* __restrict__ ko, float* __restrict__ vo)
{
    __shared__ char asb[2][64 * 128 * 2];      // [hi/lo][row][c] bf16, swizzled
    const int p0  = blockIdx.x * 64;
    const int tid = threadIdx.x;

    // stage sf tile: 1024 16B vectors per array, 2 per thread
    for (int i = tid; i < 1024; i += 512) {
        int row  = i >> 4;
        int cvec = i & 15;
        int byteoff = ((row * 128 + cvec * 8) * 2) ^ ((row & 7) << 4);
        *(bf8_t*)(asb[0] + byteoff) = *(const bf8_t*)(sfh + p0 * 128 + i * 8);
        *(bf8_t*)(asb[1] + byteoff) = *(const bf8_t*)(sfl + p0 * 128 + i * 8);
    }
    __syncthreads();

    const int lane   = tid & 63;
    const int wid    = tid >> 6;
    const int wm     = wid >> 2;       // 0..1
    const int wn     = wid & 3;        // 0..3
    const int lane15 = lane & 15;
    const int lanehi = lane >> 4;

    f4_t acc[2][6] = {};

#pragma unroll
    for (int kk = 0; kk < 128; kk += 32) {
        bf8_t ah[2], al[2];
#pragma unroll
        for (int mf = 0; mf < 2; ++mf) {
            int row = wm * 32 + mf * 16 + lane15;
            int byteoff = ((row * 128 + kk + lanehi * 8) * 2) ^ ((row & 7) << 4);
            ah[mf] = *(const bf8_t*)(asb[0] + byteoff);
            al[mf] = *(const bf8_t*)(asb[1] + byteoff);
        }
#pragma unroll
        for (int nf = 0; nf < 6; ++nf) {
            int n = wn * 96 + nf * 16 + lane15;
            bf8_t bhv = *(const bf8_t*)(w2h + n * 128 + kk + lanehi * 8);
            bf8_t blv = *(const bf8_t*)(w2l + n * 128 + kk + lanehi * 8);
#pragma unroll
            for (int mf = 0; mf < 2; ++mf) {
                acc[mf][nf] = __builtin_amdgcn_mfma_f32_16x16x32_bf16(
                    ah[mf], bhv, acc[mf][nf], 0, 0, 0);
                acc[mf][nf] = __builtin_amdgcn_mfma_f32_16x16x32_bf16(
                    al[mf], bhv, acc[mf][nf], 0, 0, 0);
                acc[mf][nf] = __builtin_amdgcn_mfma_f32_16x16x32_bf16(
                    ah[mf], blv, acc[mf][nf], 0, 0, 0);
            }
        }
    }

    const int r4 = lanehi * 4;
#pragma unroll
    for (int nf = 0; nf < 6; ++nf) {
        int n = wn * 96 + nf * 16 + lane15;
        int which = n >> 7;
        int o = n & 127;
        const float* bp = which == 0 ? qb : (which == 1 ? kb : vb);
        float bias = bp[o];
        float scale = which == 0 ? 0.0625f : 1.0f;
        float* op = which == 0 ? qo : (which == 1 ? ko : vo);
#pragma unroll
        for (int mf = 0; mf < 2; ++mf) {
            int pos = p0 + wm * 32 + mf * 16 + r4;
#pragma unroll
            for (int r = 0; r < 4; ++r)
                op[(pos + r) * CMID + o] = (acc[mf][nf][r] + bias) * scale;
        }
    }
}

// ---------------------------------------------------------------------------
// Neighborhood attention. One wave per query point (unchanged from R3).
// ---------------------------------------------------------------------------
__global__ __launch_bounds__(256) void attn_kernel(
    const float* __restrict__ q, const float* __restrict__ k,
    const float* __restrict__ v, const float* __restrict__ As,
    float* __restrict__ out)
{
    __shared__ float qs[4][CMID];
    __shared__ float aw[4][64];
    __shared__ int   nb[4][64];
    const int tid  = threadIdx.x;
    const int wv   = tid >> 6;
    const int lane = tid & 63;
    const int g    = blockIdx.x * 4 + wv;
    const int b    = g / (HH * WW);
    const int rem  = g % (HH * WW);
    const int h    = rem / WW;
    const int w    = rem % WW;

    {
        float2 qv = *(const float2*)(q + g * CMID + lane * 2);
        qs[wv][lane * 2]     = qv.x;
        qs[wv][lane * 2 + 1] = qv.y;
    }
    __syncthreads();

    const int n  = lane < 49 ? lane : 48;
    const int u  = n / 7, vvn = n % 7;
    int sh = (h >> 1) - 3; sh = sh < 0 ? 0 : (sh > 21 ? 21 : sh);
    int sw = (w >> 1) - 3; sw = sw < 0 ? 0 : (sw > 21 ? 21 : sw);
    const int ihn = (h & 1) + (sh + u) * 2;
    const int iwn = (w & 1) + (sw + vvn) * 2;
    const int base = ((b * HH + ihn) * WW + iwn) * CMID;

    float acc = 0.f;
    const float* kr = k + base;
#pragma unroll 8
    for (int c = 0; c < CMID; c += 4) {
        float4 kv = *(const float4*)(kr + c);
        float4 qv = *(const float4*)(&qs[wv][c]);
        acc += qv.x * kv.x + qv.y * kv.y + qv.z * kv.z + qv.w * kv.w;
    }
    float logit = acc + As[h * 7 + u] + As[w * 7 + vvn];
    if (lane >= 49) logit = -INFINITY;

    float m = logit;
#pragma unroll
    for (int s = 32; s > 0; s >>= 1)
        m = fmaxf(m, __shfl_xor(m, s, 64));
    const float e = (lane < 49) ? expf(logit - m) : 0.f;
    float ssum = e;
#pragma unroll
    for (int s = 32; s > 0; s >>= 1)
        ssum += __shfl_xor(ssum, s, 64);
    const float a = e / ssum;

    aw[wv][lane] = a;
    nb[wv][lane] = base;
    __syncthreads();

    const int c0 = lane * 2;
    float o0 = 0.f, o1 = 0.f;
    for (int n2 = 0; n2 < 49; ++n2) {
        const float a2 = aw[wv][n2];
        const int   bs = nb[wv][n2];
        float2 vv2 = *(const float2*)(v + bs + c0);
        o0 += a2 * vv2.x;
        o1 += a2 * vv2.y;
    }
    *(float2*)(out + g * CMID + c0) = make_float2(o0, o1);
}

// ---------------------------------------------------------------------------
extern "C" void kernel_launch(void* const* d_in, const int* in_sizes, int n_in,
                              void* d_out, int out_size, void* d_ws, size_t ws_size,
                              hipStream_t stream)
{
    const float* x  = (const float*)d_in[0];
    const float* cw = (const float*)d_in[1];
    const float* cb = (const float*)d_in[2];
    const float* qw = (const float*)d_in[3];
    const float* qb = (const float*)d_in[4];
    const float* kw = (const float*)d_in[5];
    const float* kb = (const float*)d_in[6];
    const float* vw = (const float*)d_in[7];
    const float* vb = (const float*)d_in[8];

    float* ws = (float*)d_ws;
    float* qx = ws + Q_OFF;
    float* kx = ws + K_OFF;
    float* vx = ws + V_OFF;
    float* As = ws + AS_OFF;
    unsigned short* sfh = (unsigned short*)(ws + SFH_OFF);
    unsigned short* sfl = (unsigned short*)(ws + SFL_OFF);
    unsigned short* wfh = (unsigned short*)(ws + WFH_OFF);
    unsigned short* wfl = (unsigned short*)(ws + WFL_OFF);
    unsigned short* w2h = (unsigned short*)(ws + W2H_OFF);
    unsigned short* w2l = (unsigned short*)(ws + W2L_OFF);
    float* out = (float*)d_out;

    hipLaunchKernelGGL(prep_w, dim3(288), dim3(256), 0, stream,
                       cw, qw, kw, vw, wfh, wfl, w2h, w2l);
    hipLaunchKernelGGL(tables_kernel, dim3(1), dim3(448), 0, stream, As);
    hipLaunchKernelGGL(conv_mfma, dim3(56, 2), dim3(512), 0, stream,
                       x, wfh, wfl, cb, sfh, sfl);
    hipLaunchKernelGGL(qkv_mfma, dim3(98), dim3(512), 0, stream,
                       sfh, sfl, w2h, w2l, qb, kb, vb, qx, kx, vx);
    hipLaunchKernelGGL(attn_kernel, dim3(1568), dim3(256), 0, stream,
                       qx, kx, vx, As, out);
}

// Round 6
// 159.873 us; speedup vs baseline: 1.2304x; 1.0188x over previous
//
#include <hip/hip_runtime.h>
#include <hip/hip_bf16.h>
#include <math.h>

// Problem constants (kernel_size=7, dilation=2 fixed by the bench's setup_inputs)
#define BB   2
#define HH   56
#define WW   56
#define CIN  64
#define CMID 128

typedef short bf8_t __attribute__((ext_vector_type(8)));   // 8 x bf16 (4 VGPRs)
typedef float f4_t  __attribute__((ext_vector_type(4)));   // 4 x f32 acc
typedef _Float16 h2_t __attribute__((ext_vector_type(2)));

// ws layout in floats
#define QH_OFF  0                    // q f16 (pre-scaled 1/16): 802816 h = 401408 f
#define KH_OFF  401408               // k f16
#define V_OFF   802816               // v fp32: 802816 f
#define SF_OFF  1605632              // sf fp32: 802816 f
#define AS_OFF  2408448              // 56*7 table, pre-scaled by 1/16
#define WFH_OFF 2408840              // conv w hi bf16: 9*128*64 = 36864 f
#define WFL_OFF 2445704
#define W2H_OFF 2482568              // qkv w hi bf16: 384*128 = 24576 f
#define W2L_OFF 2507144
// end 2531720 floats = 9.66 MiB

__device__ __forceinline__ unsigned short f2bf(float f) {
    unsigned int u = __builtin_bit_cast(unsigned int, f);
    u += 0x7fffu + ((u >> 16) & 1u);          // RTN-even
    return (unsigned short)(u >> 16);
}
__device__ __forceinline__ float bf2f(unsigned short h) {
    unsigned int u = ((unsigned int)h) << 16;
    return __builtin_bit_cast(float, u);
}

// ---------------------------------------------------------------------------
// Kernel 0: weight prep (dst-major => coalesced 2B writes) + PE table.
// conv: cw[o][c][seg] -> wf[seg][o][c] bf16 hi/lo
// qkv : qw/kw/vw[o][c] -> w2[(which*128+o)][c] bf16 hi/lo
// tables (block 288): A[i][j] = sum_t cos((i - idx(i,j)) * div_t) / 16
//   (grid-stride over all 392 entries — R5 bug: only wrote the first 256)
// ---------------------------------------------------------------------------
__global__ __launch_bounds__(256) void prep_w(
    const float* __restrict__ cw, const float* __restrict__ qw,
    const float* __restrict__ kw, const float* __restrict__ vw,
    unsigned short* __restrict__ wfh, unsigned short* __restrict__ wfl,
    unsigned short* __restrict__ w2h, unsigned short* __restrict__ w2l,
    float* __restrict__ As)
{
    int idx = blockIdx.x * 256 + threadIdx.x;
    if (idx < 128 * 64 * 9) {               // dst-major: coalesced writes
        int c   = idx & 63;
        int o   = (idx >> 6) & 127;
        int seg = idx >> 13;
        float wv = cw[(o * 64 + c) * 9 + seg];   // scattered read (L2-cached)
        unsigned short hi = f2bf(wv);
        wfh[idx] = hi; wfl[idx] = f2bf(wv - bf2f(hi));
    }
    if (idx < 128 * 128) {                  // both sides coalesced
        float wv = qw[idx];
        unsigned short hi = f2bf(wv);
        w2h[idx] = hi; w2l[idx] = f2bf(wv - bf2f(hi));
        wv = kw[idx];
        hi = f2bf(wv);
        w2h[16384 + idx] = hi; w2l[16384 + idx] = f2bf(wv - bf2f(hi));
        wv = vw[idx];
        hi = f2bf(wv);
        w2h[32768 + idx] = hi; w2l[32768 + idx] = f2bf(wv - bf2f(hi));
    }
    if (blockIdx.x == 288) {
        for (int t = threadIdx.x; t < 56 * 7; t += 256) {   // FIXED: grid-stride
            int i = t / 7, j = t % 7;
            int p = i >> 1;
            int start = p - 3;
            if (start < 0) start = 0;
            if (start > 21) start = 21;
            int nidx = (i & 1) + (start + j) * 2;
            float delta = (float)(i - nidx);
            float acc = 0.f;
            for (int u = 0; u < 32; ++u) {
                float d = expf(-9.210340371976184f * (float)u * 0.03125f);
                acc += cosf(delta * d);
            }
            As[t] = acc * 0.0625f;
        }
    }
}

// ---------------------------------------------------------------------------
// Conv as 9 accumulated MFMA GEMMs, double-bf16 (hi/lo) precision.
// Block = one (b,h) row: M=64 (56 w + pad), N=128, K=9*64.
// 8 waves = 2(M) x 4(N). A staged in LDS (XOR-swizzled); B from L2.
// Epilogue: +bias, fp32 coalesced stores.
// ---------------------------------------------------------------------------
__global__ __launch_bounds__(512) void conv_mfma(
    const float* __restrict__ x,
    const unsigned short* __restrict__ wfh, const unsigned short* __restrict__ wfl,
    const float* __restrict__ cb,
    float* __restrict__ sf)
{
    __shared__ char xsb[2][3 * 66 * 64 * 2];   // [hi/lo][dh][row0..65][c0..63] bf16
    const int h   = blockIdx.x;
    const int b   = blockIdx.y;
    const int tid = threadIdx.x;

    for (int idx = tid; idx < 3 * 64 * 66; idx += 512) {
        int dh  = idx / (64 * 66);
        int rem = idx % (64 * 66);
        int c   = rem / 66;
        int row = rem % 66;                    // input col = row-1
        int y   = h + dh - 1;
        int wg  = row - 1;
        float val = 0.f;
        if ((unsigned)y < HH && (unsigned)wg < WW)
            val = x[((b * CIN + c) * HH + y) * WW + wg];
        unsigned short hi = f2bf(val);
        unsigned short lo = f2bf(val - bf2f(hi));
        int byteoff = (((dh * 66 + row) * 64 + c) * 2) ^ ((row & 7) << 4);
        *(unsigned short*)(xsb[0] + byteoff) = hi;
        *(unsigned short*)(xsb[1] + byteoff) = lo;
    }
    __syncthreads();

    const int lane   = tid & 63;
    const int wid    = tid >> 6;
    const int wm     = wid >> 2;       // 0..1
    const int wn     = wid & 3;        // 0..3
    const int lane15 = lane & 15;
    const int lanehi = lane >> 4;

    f4_t acc[2][2] = {};

    for (int seg = 0; seg < 9; ++seg) {
        const int dh = seg / 3, dw = seg % 3;
        const int bbase = (seg * 128) * 64 + lanehi * 8;
#pragma unroll
        for (int kk = 0; kk < 64; kk += 32) {
            bf8_t ah[2], al[2], bh[2], bl[2];
#pragma unroll
            for (int mf = 0; mf < 2; ++mf) {
                int row = wm * 32 + mf * 16 + lane15 + dw;
                int byteoff = (((dh * 66 + row) * 64 + kk + lanehi * 8) * 2)
                              ^ ((row & 7) << 4);
                ah[mf] = *(const bf8_t*)(xsb[0] + byteoff);
                al[mf] = *(const bf8_t*)(xsb[1] + byteoff);
            }
#pragma unroll
            for (int nf = 0; nf < 2; ++nf) {
                int o = wn * 32 + nf * 16 + lane15;
                bh[nf] = *(const bf8_t*)(wfh + bbase + o * 64 + kk);
                bl[nf] = *(const bf8_t*)(wfl + bbase + o * 64 + kk);
            }
#pragma unroll
            for (int mf = 0; mf < 2; ++mf)
#pragma unroll
                for (int nf = 0; nf < 2; ++nf) {
                    acc[mf][nf] = __builtin_amdgcn_mfma_f32_16x16x32_bf16(
                        ah[mf], bh[nf], acc[mf][nf], 0, 0, 0);
                    acc[mf][nf] = __builtin_amdgcn_mfma_f32_16x16x32_bf16(
                        al[mf], bh[nf], acc[mf][nf], 0, 0, 0);
                    acc[mf][nf] = __builtin_amdgcn_mfma_f32_16x16x32_bf16(
                        ah[mf], bl[nf], acc[mf][nf], 0, 0, 0);
                }
        }
    }

    const int r4 = lanehi * 4;
#pragma unroll
    for (int mf = 0; mf < 2; ++mf) {
        int wr = wm * 32 + mf * 16 + r4;
#pragma unroll
        for (int nf = 0; nf < 2; ++nf) {
            int o = wn * 32 + nf * 16 + lane15;
            float bias = cb[o];
#pragma unroll
            for (int r = 0; r < 4; ++r) {
                int wpos = wr + r;
                if (wpos < 56)
                    sf[((b * HH + h) * WW + wpos) * CMID + o] = acc[mf][nf][r] + bias;
            }
        }
    }
}

// ---------------------------------------------------------------------------
// QKV: one GEMM M=6272, N=384 (q|k|v), K=128, double-bf16 (split done during
// LDS staging from fp32 sf). Epilogue: q,k -> f16 (q pre-scaled 1/16), v fp32.
// ---------------------------------------------------------------------------
__global__ __launch_bounds__(512) void qkv_mfma(
    const float* __restrict__ sf,
    const unsigned short* __restrict__ w2h, const unsigned short* __restrict__ w2l,
    const float* __restrict__ qb, const float* __restrict__ kb,
    const float* __restrict__ vb,
    _Float16* __restrict__ qh16, _Float16* __restrict__ kh16,
    float* __restrict__ vo)
{
    __shared__ char asb[2][64 * 128 * 2];      // [hi/lo][row][c] bf16, swizzled
    const int p0  = blockIdx.x * 64;
    const int tid = threadIdx.x;

    // stage sf tile fp32 -> bf16 hi/lo, 8 floats per iteration per thread
    for (int i = tid; i < 1024; i += 512) {
        int row = i >> 4;
        int c0  = (i & 15) * 8;
        float4 fa = *(const float4*)(sf + (p0 + row) * 128 + c0);
        float4 fb = *(const float4*)(sf + (p0 + row) * 128 + c0 + 4);
        bf8_t hi, lo;
        float fv[8] = {fa.x, fa.y, fa.z, fa.w, fb.x, fb.y, fb.z, fb.w};
#pragma unroll
        for (int j = 0; j < 8; ++j) {
            unsigned short hj = f2bf(fv[j]);
            hi[j] = (short)hj;
            lo[j] = (short)f2bf(fv[j] - bf2f(hj));
        }
        int byteoff = ((row * 128 + c0) * 2) ^ ((row & 7) << 4);
        *(bf8_t*)(asb[0] + byteoff) = hi;
        *(bf8_t*)(asb[1] + byteoff) = lo;
    }
    __syncthreads();

    const int lane   = tid & 63;
    const int wid    = tid >> 6;
    const int wm     = wid >> 2;       // 0..1
    const int wn     = wid & 3;        // 0..3
    const int lane15 = lane & 15;
    const int lanehi = lane >> 4;

    f4_t acc[2][6] = {};

#pragma unroll
    for (int kk = 0; kk < 128; kk += 32) {
        bf8_t ah[2], al[2];
#pragma unroll
        for (int mf = 0; mf < 2; ++mf) {
            int row = wm * 32 + mf * 16 + lane15;
            int byteoff = ((row * 128 + kk + lanehi * 8) * 2) ^ ((row & 7) << 4);
            ah[mf] = *(const bf8_t*)(asb[0] + byteoff);
            al[mf] = *(const bf8_t*)(asb[1] + byteoff);
        }
#pragma unroll
        for (int nf = 0; nf < 6; ++nf) {
            int n = wn * 96 + nf * 16 + lane15;
            bf8_t bhv = *(const bf8_t*)(w2h + n * 128 + kk + lanehi * 8);
            bf8_t blv = *(const bf8_t*)(w2l + n * 128 + kk + lanehi * 8);
#pragma unroll
            for (int mf = 0; mf < 2; ++mf) {
                acc[mf][nf] = __builtin_amdgcn_mfma_f32_16x16x32_bf16(
                    ah[mf], bhv, acc[mf][nf], 0, 0, 0);
                acc[mf][nf] = __builtin_amdgcn_mfma_f32_16x16x32_bf16(
                    al[mf], bhv, acc[mf][nf], 0, 0, 0);
                acc[mf][nf] = __builtin_amdgcn_mfma_f32_16x16x32_bf16(
                    ah[mf], blv, acc[mf][nf], 0, 0, 0);
            }
        }
    }

    const int r4 = lanehi * 4;
#pragma unroll
    for (int nf = 0; nf < 6; ++nf) {
        int n = wn * 96 + nf * 16 + lane15;
        int which = n >> 7;
        int o = n & 127;
        const float* bp = which == 0 ? qb : (which == 1 ? kb : vb);
        float bias = bp[o];
#pragma unroll
        for (int mf = 0; mf < 2; ++mf) {
            int pos = p0 + wm * 32 + mf * 16 + r4;
#pragma unroll
            for (int r = 0; r < 4; ++r) {
                float val = acc[mf][nf][r] + bias;
                int di = (pos + r) * CMID + o;
                if (which == 0)      qh16[di] = (_Float16)(val * 0.0625f);
                else if (which == 1) kh16[di] = (_Float16)val;
                else                 vo[di]   = val;
            }
        }
    }
}

// ---------------------------------------------------------------------------
// Neighborhood attention. One wave per query point. q,k f16 (q pre-scaled);
// QK via v_dot2_f32_f16; v fp32 with wave-uniform coalesced PV loads.
// ---------------------------------------------------------------------------
__global__ __launch_bounds__(256) void attn_kernel(
    const _Float16* __restrict__ qh, const _Float16* __restrict__ kh,
    const float* __restrict__ v, const float* __restrict__ As,
    float* __restrict__ out)
{
    __shared__ _Float16 qs[4][CMID];
    __shared__ float aw[4][64];
    __shared__ int   nb[4][64];
    const int tid  = threadIdx.x;
    const int wv   = tid >> 6;
    const int lane = tid & 63;
    const int g    = blockIdx.x * 4 + wv;
    const int b    = g / (HH * WW);
    const int rem  = g % (HH * WW);
    const int h    = rem / WW;
    const int w    = rem % WW;

    {   // q row -> LDS (coalesced 4B/lane)
        unsigned int qv = *(const unsigned int*)(qh + g * CMID + lane * 2);
        *(unsigned int*)(&qs[wv][lane * 2]) = qv;
    }
    __syncthreads();

    const int n  = lane < 49 ? lane : 48;
    const int u  = n / 7, vvn = n % 7;
    int sh = (h >> 1) - 3; sh = sh < 0 ? 0 : (sh > 21 ? 21 : sh);
    int sw = (w >> 1) - 3; sw = sw < 0 ? 0 : (sw > 21 ? 21 : sw);
    const int ihn = (h & 1) + (sh + u) * 2;
    const int iwn = (w & 1) + (sw + vvn) * 2;
    const int base = ((b * HH + ihn) * WW + iwn) * CMID;

    float acc = 0.f;
    const uint4* kr = (const uint4*)(kh + base);
#pragma unroll
    for (int c = 0; c < 16; ++c) {            // 16 x 16B gathers (8 f16 each)
        uint4 kv = kr[c];
        uint4 qv = *(const uint4*)(&qs[wv][c * 8]);   // LDS broadcast
#if __has_builtin(__builtin_amdgcn_fdot2)
        acc = __builtin_amdgcn_fdot2(__builtin_bit_cast(h2_t, kv.x),
                                     __builtin_bit_cast(h2_t, qv.x), acc, false);
        acc = __builtin_amdgcn_fdot2(__builtin_bit_cast(h2_t, kv.y),
                                     __builtin_bit_cast(h2_t, qv.y), acc, false);
        acc = __builtin_amdgcn_fdot2(__builtin_bit_cast(h2_t, kv.z),
                                     __builtin_bit_cast(h2_t, qv.z), acc, false);
        acc = __builtin_amdgcn_fdot2(__builtin_bit_cast(h2_t, kv.w),
                                     __builtin_bit_cast(h2_t, qv.w), acc, false);
#else
        {
            h2_t ka[4] = {__builtin_bit_cast(h2_t, kv.x), __builtin_bit_cast(h2_t, kv.y),
                          __builtin_bit_cast(h2_t, kv.z), __builtin_bit_cast(h2_t, kv.w)};
            h2_t qa[4] = {__builtin_bit_cast(h2_t, qv.x), __builtin_bit_cast(h2_t, qv.y),
                          __builtin_bit_cast(h2_t, qv.z), __builtin_bit_cast(h2_t, qv.w)};
#pragma unroll
            for (int j = 0; j < 4; ++j)
                acc += (float)ka[j][0] * (float)qa[j][0] + (float)ka[j][1] * (float)qa[j][1];
        }
#endif
    }
    float logit = acc + As[h * 7 + u] + As[w * 7 + vvn];
    if (lane >= 49) logit = -INFINITY;

    float m = logit;
#pragma unroll
    for (int s = 32; s > 0; s >>= 1)
        m = fmaxf(m, __shfl_xor(m, s, 64));
    const float e = (lane < 49) ? expf(logit - m) : 0.f;
    float ssum = e;
#pragma unroll
    for (int s = 32; s > 0; s >>= 1)
        ssum += __shfl_xor(ssum, s, 64);
    const float a = e / ssum;

    aw[wv][lane] = a;
    nb[wv][lane] = base;
    __syncthreads();

    const int c0 = lane * 2;
    float o0 = 0.f, o1 = 0.f;
    for (int n2 = 0; n2 < 49; ++n2) {
        const float a2 = aw[wv][n2];
        const int   bs = nb[wv][n2];
        float2 vv2 = *(const float2*)(v + bs + c0);   // wave-uniform row, coalesced
        o0 += a2 * vv2.x;
        o1 += a2 * vv2.y;
    }
    *(float2*)(out + g * CMID + c0) = make_float2(o0, o1);
}

// ---------------------------------------------------------------------------
extern "C" void kernel_launch(void* const* d_in, const int* in_sizes, int n_in,
                              void* d_out, int out_size, void* d_ws, size_t ws_size,
                              hipStream_t stream)
{
    const float* x  = (const float*)d_in[0];
    const float* cw = (const float*)d_in[1];
    const float* cb = (const float*)d_in[2];
    const float* qw = (const float*)d_in[3];
    const float* qb = (const float*)d_in[4];
    const float* kw = (const float*)d_in[5];
    const float* kb = (const float*)d_in[6];
    const float* vw = (const float*)d_in[7];
    const float* vb = (const float*)d_in[8];

    float* ws = (float*)d_ws;
    _Float16* qh = (_Float16*)(ws + QH_OFF);
    _Float16* khx = (_Float16*)(ws + KH_OFF);
    float* vx = ws + V_OFF;
    float* sf = ws + SF_OFF;
    float* As = ws + AS_OFF;
    unsigned short* wfh = (unsigned short*)(ws + WFH_OFF);
    unsigned short* wfl = (unsigned short*)(ws + WFL_OFF);
    unsigned short* w2h = (unsigned short*)(ws + W2H_OFF);
    unsigned short* w2l = (unsigned short*)(ws + W2L_OFF);
    float* out = (float*)d_out;

    hipLaunchKernelGGL(prep_w, dim3(289), dim3(256), 0, stream,
                       cw, qw, kw, vw, wfh, wfl, w2h, w2l, As);
    hipLaunchKernelGGL(conv_mfma, dim3(56, 2), dim3(512), 0, stream,
                       x, wfh, wfl, cb, sf);
    hipLaunchKernelGGL(qkv_mfma, dim3(98), dim3(512), 0, stream,
                       sf, w2h, w2l, qb, kb, vb, qh, khx, vx);
    hipLaunchKernelGGL(attn_kernel, dim3(1568), dim3(256), 0, stream,
                       qh, khx, vx, As, out);
}

// Round 7
// 146.966 us; speedup vs baseline: 1.3385x; 1.0878x over previous
//
#include <hip/hip_runtime.h>
#include <hip/hip_bf16.h>
#include <math.h>

// Problem constants (kernel_size=7, dilation=2 fixed by the bench's setup_inputs)
#define BB   2
#define HH   56
#define WW   56
#define CIN  64
#define CMID 128

typedef short bf8_t __attribute__((ext_vector_type(8)));   // 8 x bf16 (4 VGPRs)
typedef float f4_t  __attribute__((ext_vector_type(4)));   // 4 x f32 acc
typedef _Float16 h2_t __attribute__((ext_vector_type(2)));

// ws layout in floats
#define QH_OFF  0                    // q f16 (pre-scaled 1/16): 802816 h = 401408 f
#define KH_OFF  401408               // k f16
#define V_OFF   802816               // v fp32: 802816 f
#define SF_OFF  1605632              // sf fp32: 802816 f
#define AS_OFF  2408448              // 56*7 table, pre-scaled by 1/16
#define WFH_OFF 2408840              // conv w hi bf16 frag-major: 9*2*8*64*8 = 73728 h = 36864 f
#define WFL_OFF 2445704
#define W2H_OFF 2482568              // qkv w hi bf16 frag-major: 4*24*64*8 = 49152 h = 24576 f
#define W2L_OFF 2507144
// end 2531720 floats = 9.66 MiB

__device__ __forceinline__ unsigned short f2bf(float f) {
    unsigned int u = __builtin_bit_cast(unsigned int, f);
    u += 0x7fffu + ((u >> 16) & 1u);          // RTN-even
    return (unsigned short)(u >> 16);
}
__device__ __forceinline__ float bf2f(unsigned short h) {
    unsigned int u = ((unsigned int)h) << 16;
    return __builtin_bit_cast(float, u);
}

// ---------------------------------------------------------------------------
// Kernel 0: weight prep into MFMA-fragment-major order + PE table.
// B-fragment for mfma_16x16x32: lane l holds col=l&15, k=(l>>4)*8..+8.
// conv: wf[seg][kk32][o16][lane][8]  (flat idx below) -> every B-load is a
//       lane-contiguous 1KB read.
// qkv : w2[kk32][n16][lane][8], n = which*128+o stacked q|k|v.
// ---------------------------------------------------------------------------
__global__ __launch_bounds__(256) void prep_w(
    const float* __restrict__ cw, const float* __restrict__ qw,
    const float* __restrict__ kw, const float* __restrict__ vw,
    unsigned short* __restrict__ wfh, unsigned short* __restrict__ wfl,
    unsigned short* __restrict__ w2h, unsigned short* __restrict__ w2l,
    float* __restrict__ As)
{
    int idx = blockIdx.x * 256 + threadIdx.x;
    if (idx < 9 * 2 * 8 * 64 * 8) {          // conv weights, dst-major
        int j    = idx & 7;
        int lane = (idx >> 3) & 63;
        int o16  = (idx >> 9) & 7;
        int kk32 = (idx >> 12) & 1;
        int seg  = idx >> 13;                // 0..8
        int o = o16 * 16 + (lane & 15);
        int c = kk32 * 32 + (lane >> 4) * 8 + j;
        float wv = cw[(o * 64 + c) * 9 + seg];
        unsigned short hi = f2bf(wv);
        wfh[idx] = hi; wfl[idx] = f2bf(wv - bf2f(hi));
    }
    if (idx < 4 * 24 * 64 * 8) {             // qkv weights, dst-major
        int j    = idx & 7;
        int lane = (idx >> 3) & 63;
        int rest = idx >> 9;                 // 0..95
        int n16  = rest % 24;
        int kk32 = rest / 24;                // 0..3
        int n = n16 * 16 + (lane & 15);      // 0..383
        int c = kk32 * 32 + (lane >> 4) * 8 + j;
        int which = n >> 7, o = n & 127;
        const float* src = which == 0 ? qw : (which == 1 ? kw : vw);
        float wv = src[o * 128 + c];
        unsigned short hi = f2bf(wv);
        w2h[idx] = hi; w2l[idx] = f2bf(wv - bf2f(hi));
    }
    if (blockIdx.x == 288) {
        for (int t = threadIdx.x; t < 56 * 7; t += 256) {
            int i = t / 7, j = t % 7;
            int p = i >> 1;
            int start = p - 3;
            if (start < 0) start = 0;
            if (start > 21) start = 21;
            int nidx = (i & 1) + (start + j) * 2;
            float delta = (float)(i - nidx);
            float acc = 0.f;
            for (int u = 0; u < 32; ++u) {
                float d = expf(-9.210340371976184f * (float)u * 0.03125f);
                acc += cosf(delta * d);
            }
            As[t] = acc * 0.0625f;
        }
    }
}

// ---------------------------------------------------------------------------
// Conv as 9 accumulated MFMA GEMMs, double-bf16 (hi/lo) precision.
// Block = one (b,h) row: M=64 (56 w + pad), N=128, K=9*64.
// 8 waves = 2(M) x 4(N). A staged in LDS (XOR-swizzled); B loads now
// fragment-major (lane-contiguous 1KB). Epilogue: +bias, fp32 stores.
// ---------------------------------------------------------------------------
__global__ __launch_bounds__(512) void conv_mfma(
    const float* __restrict__ x,
    const unsigned short* __restrict__ wfh, const unsigned short* __restrict__ wfl,
    const float* __restrict__ cb,
    float* __restrict__ sf)
{
    __shared__ char xsb[2][3 * 66 * 64 * 2];   // [hi/lo][dh][row0..65][c0..63] bf16
    const int h   = blockIdx.x;
    const int b   = blockIdx.y;
    const int tid = threadIdx.x;

    for (int idx = tid; idx < 3 * 64 * 66; idx += 512) {
        int dh  = idx / (64 * 66);
        int rem = idx % (64 * 66);
        int c   = rem / 66;
        int row = rem % 66;                    // input col = row-1
        int y   = h + dh - 1;
        int wg  = row - 1;
        float val = 0.f;
        if ((unsigned)y < HH && (unsigned)wg < WW)
            val = x[((b * CIN + c) * HH + y) * WW + wg];
        unsigned short hi = f2bf(val);
        unsigned short lo = f2bf(val - bf2f(hi));
        int byteoff = (((dh * 66 + row) * 64 + c) * 2) ^ ((row & 7) << 4);
        *(unsigned short*)(xsb[0] + byteoff) = hi;
        *(unsigned short*)(xsb[1] + byteoff) = lo;
    }
    __syncthreads();

    const int lane   = tid & 63;
    const int wid    = tid >> 6;
    const int wm     = wid >> 2;       // 0..1
    const int wn     = wid & 3;        // 0..3
    const int lane15 = lane & 15;
    const int lanehi = lane >> 4;

    f4_t acc[2][2] = {};

    for (int seg = 0; seg < 9; ++seg) {
        const int dh = seg / 3, dw = seg % 3;
#pragma unroll
        for (int kk32 = 0; kk32 < 2; ++kk32) {
            bf8_t ah[2], al[2], bh[2], bl[2];
#pragma unroll
            for (int mf = 0; mf < 2; ++mf) {
                int row = wm * 32 + mf * 16 + lane15 + dw;
                int byteoff = (((dh * 66 + row) * 64 + kk32 * 32 + lanehi * 8) * 2)
                              ^ ((row & 7) << 4);
                ah[mf] = *(const bf8_t*)(xsb[0] + byteoff);
                al[mf] = *(const bf8_t*)(xsb[1] + byteoff);
            }
#pragma unroll
            for (int nf = 0; nf < 2; ++nf) {
                int fidx = (((seg * 2 + kk32) * 8 + (wn * 2 + nf)) * 64 + lane) * 8;
                bh[nf] = *(const bf8_t*)(wfh + fidx);   // lane-contiguous
                bl[nf] = *(const bf8_t*)(wfl + fidx);
            }
#pragma unroll
            for (int mf = 0; mf < 2; ++mf)
#pragma unroll
                for (int nf = 0; nf < 2; ++nf) {
                    acc[mf][nf] = __builtin_amdgcn_mfma_f32_16x16x32_bf16(
                        ah[mf], bh[nf], acc[mf][nf], 0, 0, 0);
                    acc[mf][nf] = __builtin_amdgcn_mfma_f32_16x16x32_bf16(
                        al[mf], bh[nf], acc[mf][nf], 0, 0, 0);
                    acc[mf][nf] = __builtin_amdgcn_mfma_f32_16x16x32_bf16(
                        ah[mf], bl[nf], acc[mf][nf], 0, 0, 0);
                }
        }
    }

    const int r4 = lanehi * 4;
#pragma unroll
    for (int mf = 0; mf < 2; ++mf) {
        int wr = wm * 32 + mf * 16 + r4;
#pragma unroll
        for (int nf = 0; nf < 2; ++nf) {
            int o = wn * 32 + nf * 16 + lane15;
            float bias = cb[o];
#pragma unroll
            for (int r = 0; r < 4; ++r) {
                int wpos = wr + r;
                if (wpos < 56)
                    sf[((b * HH + h) * WW + wpos) * CMID + o] = acc[mf][nf][r] + bias;
            }
        }
    }
}

// ---------------------------------------------------------------------------
// QKV: GEMM M=6272, N=384 (q|k|v), K=128, double-bf16, fragment-major B.
// Block: 32 positions (196 blocks); 8 waves = 2(M) x 4(N), wave tile 16x96.
// Epilogue: q,k -> f16 (q pre-scaled 1/16), v fp32.
// ---------------------------------------------------------------------------
__global__ __launch_bounds__(512) void qkv_mfma(
    const float* __restrict__ sf,
    const unsigned short* __restrict__ w2h, const unsigned short* __restrict__ w2l,
    const float* __restrict__ qb, const float* __restrict__ kb,
    const float* __restrict__ vb,
    _Float16* __restrict__ qh16, _Float16* __restrict__ kh16,
    float* __restrict__ vo)
{
    __shared__ char asb[2][32 * 128 * 2];      // [hi/lo][row][c] bf16, swizzled
    const int p0  = blockIdx.x * 32;
    const int tid = threadIdx.x;

    {   // stage sf tile fp32 -> bf16 hi/lo, 8 floats per thread (512 = 32*16)
        int row = tid >> 4;
        int c0  = (tid & 15) * 8;
        float4 fa = *(const float4*)(sf + (p0 + row) * 128 + c0);
        float4 fb = *(const float4*)(sf + (p0 + row) * 128 + c0 + 4);
        bf8_t hi, lo;
        float fv[8] = {fa.x, fa.y, fa.z, fa.w, fb.x, fb.y, fb.z, fb.w};
#pragma unroll
        for (int j = 0; j < 8; ++j) {
            unsigned short hj = f2bf(fv[j]);
            hi[j] = (short)hj;
            lo[j] = (short)f2bf(fv[j] - bf2f(hj));
        }
        int byteoff = ((row * 128 + c0) * 2) ^ ((row & 7) << 4);
        *(bf8_t*)(asb[0] + byteoff) = hi;
        *(bf8_t*)(asb[1] + byteoff) = lo;
    }
    __syncthreads();

    const int lane   = tid & 63;
    const int wid    = tid >> 6;
    const int wm     = wid >> 2;       // 0..1
    const int wn     = wid & 3;        // 0..3
    const int lane15 = lane & 15;
    const int lanehi = lane >> 4;

    f4_t acc[6] = {};

#pragma unroll
    for (int kk32 = 0; kk32 < 4; ++kk32) {
        bf8_t ah, al;
        {
            int row = wm * 16 + lane15;
            int byteoff = ((row * 128 + kk32 * 32 + lanehi * 8) * 2) ^ ((row & 7) << 4);
            ah = *(const bf8_t*)(asb[0] + byteoff);
            al = *(const bf8_t*)(asb[1] + byteoff);
        }
#pragma unroll
        for (int nf = 0; nf < 6; ++nf) {
            int fidx = ((kk32 * 24 + wn * 6 + nf) * 64 + lane) * 8;
            bf8_t bhv = *(const bf8_t*)(w2h + fidx);    // lane-contiguous
            bf8_t blv = *(const bf8_t*)(w2l + fidx);
            acc[nf] = __builtin_amdgcn_mfma_f32_16x16x32_bf16(ah, bhv, acc[nf], 0, 0, 0);
            acc[nf] = __builtin_amdgcn_mfma_f32_16x16x32_bf16(al, bhv, acc[nf], 0, 0, 0);
            acc[nf] = __builtin_amdgcn_mfma_f32_16x16x32_bf16(ah, blv, acc[nf], 0, 0, 0);
        }
    }

    const int r4 = lanehi * 4;
#pragma unroll
    for (int nf = 0; nf < 6; ++nf) {
        int n = wn * 96 + nf * 16 + lane15;
        int which = n >> 7;
        int o = n & 127;
        const float* bp = which == 0 ? qb : (which == 1 ? kb : vb);
        float bias = bp[o];
        int pos = p0 + wm * 16 + r4;
#pragma unroll
        for (int r = 0; r < 4; ++r) {
            float val = acc[nf][r] + bias;
            int di = (pos + r) * CMID + o;
            if (which == 0)      qh16[di] = (_Float16)(val * 0.0625f);
            else if (which == 1) kh16[di] = (_Float16)val;
            else                 vo[di]   = val;
        }
    }
}

// ---------------------------------------------------------------------------
// Neighborhood attention. One wave per query point. q,k f16 (q pre-scaled);
// QK via v_dot2_f32_f16; v fp32 with wave-uniform coalesced PV loads.
// ---------------------------------------------------------------------------
__global__ __launch_bounds__(256) void attn_kernel(
    const _Float16* __restrict__ qh, const _Float16* __restrict__ kh,
    const float* __restrict__ v, const float* __restrict__ As,
    float* __restrict__ out)
{
    __shared__ _Float16 qs[4][CMID];
    __shared__ float aw[4][64];
    __shared__ int   nb[4][64];
    const int tid  = threadIdx.x;
    const int wv   = tid >> 6;
    const int lane = tid & 63;
    const int g    = blockIdx.x * 4 + wv;
    const int b    = g / (HH * WW);
    const int rem  = g % (HH * WW);
    const int h    = rem / WW;
    const int w    = rem % WW;

    {   // q row -> LDS (coalesced 4B/lane)
        unsigned int qv = *(const unsigned int*)(qh + g * CMID + lane * 2);
        *(unsigned int*)(&qs[wv][lane * 2]) = qv;
    }
    __syncthreads();

    const int n  = lane < 49 ? lane : 48;
    const int u  = n / 7, vvn = n % 7;
    int sh = (h >> 1) - 3; sh = sh < 0 ? 0 : (sh > 21 ? 21 : sh);
    int sw = (w >> 1) - 3; sw = sw < 0 ? 0 : (sw > 21 ? 21 : sw);
    const int ihn = (h & 1) + (sh + u) * 2;
    const int iwn = (w & 1) + (sw + vvn) * 2;
    const int base = ((b * HH + ihn) * WW + iwn) * CMID;

    float acc = 0.f;
    const uint4* kr = (const uint4*)(kh + base);
#pragma unroll
    for (int c = 0; c < 16; ++c) {            // 16 x 16B gathers (8 f16 each)
        uint4 kv = kr[c];
        uint4 qv = *(const uint4*)(&qs[wv][c * 8]);   // LDS broadcast
#if __has_builtin(__builtin_amdgcn_fdot2)
        acc = __builtin_amdgcn_fdot2(__builtin_bit_cast(h2_t, kv.x),
                                     __builtin_bit_cast(h2_t, qv.x), acc, false);
        acc = __builtin_amdgcn_fdot2(__builtin_bit_cast(h2_t, kv.y),
                                     __builtin_bit_cast(h2_t, qv.y), acc, false);
        acc = __builtin_amdgcn_fdot2(__builtin_bit_cast(h2_t, kv.z),
                                     __builtin_bit_cast(h2_t, qv.z), acc, false);
        acc = __builtin_amdgcn_fdot2(__builtin_bit_cast(h2_t, kv.w),
                                     __builtin_bit_cast(h2_t, qv.w), acc, false);
#else
        {
            h2_t ka[4] = {__builtin_bit_cast(h2_t, kv.x), __builtin_bit_cast(h2_t, kv.y),
                          __builtin_bit_cast(h2_t, kv.z), __builtin_bit_cast(h2_t, kv.w)};
            h2_t qa[4] = {__builtin_bit_cast(h2_t, qv.x), __builtin_bit_cast(h2_t, qv.y),
                          __builtin_bit_cast(h2_t, qv.z), __builtin_bit_cast(h2_t, qv.w)};
#pragma unroll
            for (int j = 0; j < 4; ++j)
                acc += (float)ka[j][0] * (float)qa[j][0] + (float)ka[j][1] * (float)qa[j][1];
        }
#endif
    }
    float logit = acc + As[h * 7 + u] + As[w * 7 + vvn];
    if (lane >= 49) logit = -INFINITY;

    float m = logit;
#pragma unroll
    for (int s = 32; s > 0; s >>= 1)
        m = fmaxf(m, __shfl_xor(m, s, 64));
    const float e = (lane < 49) ? expf(logit - m) : 0.f;
    float ssum = e;
#pragma unroll
    for (int s = 32; s > 0; s >>= 1)
        ssum += __shfl_xor(ssum, s, 64);
    const float a = e / ssum;

    aw[wv][lane] = a;
    nb[wv][lane] = base;
    __syncthreads();

    const int c0 = lane * 2;
    float o0 = 0.f, o1 = 0.f;
    for (int n2 = 0; n2 < 49; ++n2) {
        const float a2 = aw[wv][n2];
        const int   bs = nb[wv][n2];
        float2 vv2 = *(const float2*)(v + bs + c0);   // wave-uniform row, coalesced
        o0 += a2 * vv2.x;
        o1 += a2 * vv2.y;
    }
    *(float2*)(out + g * CMID + c0) = make_float2(o0, o1);
}

// ---------------------------------------------------------------------------
extern "C" void kernel_launch(void* const* d_in, const int* in_sizes, int n_in,
                              void* d_out, int out_size, void* d_ws, size_t ws_size,
                              hipStream_t stream)
{
    const float* x  = (const float*)d_in[0];
    const float* cw = (const float*)d_in[1];
    const float* cb = (const float*)d_in[2];
    const float* qw = (const float*)d_in[3];
    const float* qb = (const float*)d_in[4];
    const float* kw = (const float*)d_in[5];
    const float* kb = (const float*)d_in[6];
    const float* vw = (const float*)d_in[7];
    const float* vb = (const float*)d_in[8];

    float* ws = (float*)d_ws;
    _Float16* qh = (_Float16*)(ws + QH_OFF);
    _Float16* khx = (_Float16*)(ws + KH_OFF);
    float* vx = ws + V_OFF;
    float* sf = ws + SF_OFF;
    float* As = ws + AS_OFF;
    unsigned short* wfh = (unsigned short*)(ws + WFH_OFF);
    unsigned short* wfl = (unsigned short*)(ws + WFL_OFF);
    unsigned short* w2h = (unsigned short*)(ws + W2H_OFF);
    unsigned short* w2l = (unsigned short*)(ws + W2L_OFF);
    float* out = (float*)d_out;

    hipLaunchKernelGGL(prep_w, dim3(289), dim3(256), 0, stream,
                       cw, qw, kw, vw, wfh, wfl, w2h, w2l, As);
    hipLaunchKernelGGL(conv_mfma, dim3(56, 2), dim3(512), 0, stream,
                       x, wfh, wfl, cb, sf);
    hipLaunchKernelGGL(qkv_mfma, dim3(196), dim3(512), 0, stream,
                       sf, w2h, w2l, qb, kb, vb, qh, khx, vx);
    hipLaunchKernelGGL(attn_kernel, dim3(1568), dim3(256), 0, stream,
                       qh, khx, vx, As, out);
}

// Round 8
// 132.576 us; speedup vs baseline: 1.4838x; 1.1085x over previous
//
#include <hip/hip_runtime.h>
#include <hip/hip_bf16.h>
#include <math.h>

// Problem constants (kernel_size=7, dilation=2 fixed by the bench's setup_inputs)
#define BB   2
#define HH   56
#define WW   56
#define CIN  64
#define CMID 128

typedef short bf8_t __attribute__((ext_vector_type(8)));   // 8 x bf16 (4 VGPRs)
typedef float f4_t  __attribute__((ext_vector_type(4)));   // 4 x f32 acc
typedef _Float16 h2_t __attribute__((ext_vector_type(2)));
typedef _Float16 h8_t __attribute__((ext_vector_type(8))); // 8 x f16 (4 VGPRs)

// ws layout in floats
#define QH_OFF  0                    // q f16 (pre-scaled 1/16): 802816 h = 401408 f
#define KH_OFF  401408               // k f16
#define V_OFF   802816               // v fp32: 802816 f
#define SF_OFF  1605632              // sf fp32: 802816 f
#define AS_OFF  2408448              // 56*7 table, pre-scaled by 1/16
#define WFH_OFF 2408840              // conv w hi bf16 frag-major
#define WFL_OFF 2445704
#define W2H_OFF 2482568              // qkv w hi bf16 frag-major
#define W2L_OFF 2507144
// end 2531720 floats = 9.66 MiB

__device__ __forceinline__ unsigned short f2bf(float f) {
    unsigned int u = __builtin_bit_cast(unsigned int, f);
    u += 0x7fffu + ((u >> 16) & 1u);          // RTN-even
    return (unsigned short)(u >> 16);
}
__device__ __forceinline__ float bf2f(unsigned short h) {
    unsigned int u = ((unsigned int)h) << 16;
    return __builtin_bit_cast(float, u);
}

// ---------------------------------------------------------------------------
// Kernel 0: weight prep into MFMA-fragment-major order + PE table.
// ---------------------------------------------------------------------------
__global__ __launch_bounds__(256) void prep_w(
    const float* __restrict__ cw, const float* __restrict__ qw,
    const float* __restrict__ kw, const float* __restrict__ vw,
    unsigned short* __restrict__ wfh, unsigned short* __restrict__ wfl,
    unsigned short* __restrict__ w2h, unsigned short* __restrict__ w2l,
    float* __restrict__ As)
{
    int idx = blockIdx.x * 256 + threadIdx.x;
    if (idx < 9 * 2 * 8 * 64 * 8) {          // conv weights, dst-major
        int j    = idx & 7;
        int lane = (idx >> 3) & 63;
        int o16  = (idx >> 9) & 7;
        int kk32 = (idx >> 12) & 1;
        int seg  = idx >> 13;                // 0..8
        int o = o16 * 16 + (lane & 15);
        int c = kk32 * 32 + (lane >> 4) * 8 + j;
        float wv = cw[(o * 64 + c) * 9 + seg];
        unsigned short hi = f2bf(wv);
        wfh[idx] = hi; wfl[idx] = f2bf(wv - bf2f(hi));
    }
    if (idx < 4 * 24 * 64 * 8) {             // qkv weights, dst-major
        int j    = idx & 7;
        int lane = (idx >> 3) & 63;
        int rest = idx >> 9;                 // 0..95
        int n16  = rest % 24;
        int kk32 = rest / 24;                // 0..3
        int n = n16 * 16 + (lane & 15);      // 0..383
        int c = kk32 * 32 + (lane >> 4) * 8 + j;
        int which = n >> 7, o = n & 127;
        const float* src = which == 0 ? qw : (which == 1 ? kw : vw);
        float wv = src[o * 128 + c];
        unsigned short hi = f2bf(wv);
        w2h[idx] = hi; w2l[idx] = f2bf(wv - bf2f(hi));
    }
    if (blockIdx.x == 288) {
        for (int t = threadIdx.x; t < 56 * 7; t += 256) {
            int i = t / 7, j = t % 7;
            int p = i >> 1;
            int start = p - 3;
            if (start < 0) start = 0;
            if (start > 21) start = 21;
            int nidx = (i & 1) + (start + j) * 2;
            float delta = (float)(i - nidx);
            float acc = 0.f;
            for (int u = 0; u < 32; ++u) {
                float d = expf(-9.210340371976184f * (float)u * 0.03125f);
                acc += cosf(delta * d);
            }
            As[t] = acc * 0.0625f;
        }
    }
}

// ---------------------------------------------------------------------------
// Conv as 9 accumulated MFMA GEMMs, double-bf16 (hi/lo). (unchanged R7)
// ---------------------------------------------------------------------------
__global__ __launch_bounds__(512) void conv_mfma(
    const float* __restrict__ x,
    const unsigned short* __restrict__ wfh, const unsigned short* __restrict__ wfl,
    const float* __restrict__ cb,
    float* __restrict__ sf)
{
    __shared__ char xsb[2][3 * 66 * 64 * 2];   // [hi/lo][dh][row0..65][c0..63] bf16
    const int h   = blockIdx.x;
    const int b   = blockIdx.y;
    const int tid = threadIdx.x;

    for (int idx = tid; idx < 3 * 64 * 66; idx += 512) {
        int dh  = idx / (64 * 66);
        int rem = idx % (64 * 66);
        int c   = rem / 66;
        int row = rem % 66;                    // input col = row-1
        int y   = h + dh - 1;
        int wg  = row - 1;
        float val = 0.f;
        if ((unsigned)y < HH && (unsigned)wg < WW)
            val = x[((b * CIN + c) * HH + y) * WW + wg];
        unsigned short hi = f2bf(val);
        unsigned short lo = f2bf(val - bf2f(hi));
        int byteoff = (((dh * 66 + row) * 64 + c) * 2) ^ ((row & 7) << 4);
        *(unsigned short*)(xsb[0] + byteoff) = hi;
        *(unsigned short*)(xsb[1] + byteoff) = lo;
    }
    __syncthreads();

    const int lane   = tid & 63;
    const int wid    = tid >> 6;
    const int wm     = wid >> 2;       // 0..1
    const int wn     = wid & 3;        // 0..3
    const int lane15 = lane & 15;
    const int lanehi = lane >> 4;

    f4_t acc[2][2] = {};

    for (int seg = 0; seg < 9; ++seg) {
        const int dh = seg / 3, dw = seg % 3;
#pragma unroll
        for (int kk32 = 0; kk32 < 2; ++kk32) {
            bf8_t ah[2], al[2], bh[2], bl[2];
#pragma unroll
            for (int mf = 0; mf < 2; ++mf) {
                int row = wm * 32 + mf * 16 + lane15 + dw;
                int byteoff = (((dh * 66 + row) * 64 + kk32 * 32 + lanehi * 8) * 2)
                              ^ ((row & 7) << 4);
                ah[mf] = *(const bf8_t*)(xsb[0] + byteoff);
                al[mf] = *(const bf8_t*)(xsb[1] + byteoff);
            }
#pragma unroll
            for (int nf = 0; nf < 2; ++nf) {
                int fidx = (((seg * 2 + kk32) * 8 + (wn * 2 + nf)) * 64 + lane) * 8;
                bh[nf] = *(const bf8_t*)(wfh + fidx);   // lane-contiguous
                bl[nf] = *(const bf8_t*)(wfl + fidx);
            }
#pragma unroll
            for (int mf = 0; mf < 2; ++mf)
#pragma unroll
                for (int nf = 0; nf < 2; ++nf) {
                    acc[mf][nf] = __builtin_amdgcn_mfma_f32_16x16x32_bf16(
                        ah[mf], bh[nf], acc[mf][nf], 0, 0, 0);
                    acc[mf][nf] = __builtin_amdgcn_mfma_f32_16x16x32_bf16(
                        al[mf], bh[nf], acc[mf][nf], 0, 0, 0);
                    acc[mf][nf] = __builtin_amdgcn_mfma_f32_16x16x32_bf16(
                        ah[mf], bl[nf], acc[mf][nf], 0, 0, 0);
                }
        }
    }

    const int r4 = lanehi * 4;
#pragma unroll
    for (int mf = 0; mf < 2; ++mf) {
        int wr = wm * 32 + mf * 16 + r4;
#pragma unroll
        for (int nf = 0; nf < 2; ++nf) {
            int o = wn * 32 + nf * 16 + lane15;
            float bias = cb[o];
#pragma unroll
            for (int r = 0; r < 4; ++r) {
                int wpos = wr + r;
                if (wpos < 56)
                    sf[((b * HH + h) * WW + wpos) * CMID + o] = acc[mf][nf][r] + bias;
            }
        }
    }
}

// ---------------------------------------------------------------------------
// QKV: GEMM M=6272, N=384 (q|k|v), K=128, double-bf16, frag-major B.
// (unchanged R7)
// ---------------------------------------------------------------------------
__global__ __launch_bounds__(512) void qkv_mfma(
    const float* __restrict__ sf,
    const unsigned short* __restrict__ w2h, const unsigned short* __restrict__ w2l,
    const float* __restrict__ qb, const float* __restrict__ kb,
    const float* __restrict__ vb,
    _Float16* __restrict__ qh16, _Float16* __restrict__ kh16,
    float* __restrict__ vo)
{
    __shared__ char asb[2][32 * 128 * 2];      // [hi/lo][row][c] bf16, swizzled
    const int p0  = blockIdx.x * 32;
    const int tid = threadIdx.x;

    {   // stage sf tile fp32 -> bf16 hi/lo
        int row = tid >> 4;
        int c0  = (tid & 15) * 8;
        float4 fa = *(const float4*)(sf + (p0 + row) * 128 + c0);
        float4 fb = *(const float4*)(sf + (p0 + row) * 128 + c0 + 4);
        bf8_t hi, lo;
        float fv[8] = {fa.x, fa.y, fa.z, fa.w, fb.x, fb.y, fb.z, fb.w};
#pragma unroll
        for (int j = 0; j < 8; ++j) {
            unsigned short hj = f2bf(fv[j]);
            hi[j] = (short)hj;
            lo[j] = (short)f2bf(fv[j] - bf2f(hj));
        }
        int byteoff = ((row * 128 + c0) * 2) ^ ((row & 7) << 4);
        *(bf8_t*)(asb[0] + byteoff) = hi;
        *(bf8_t*)(asb[1] + byteoff) = lo;
    }
    __syncthreads();

    const int lane   = tid & 63;
    const int wid    = tid >> 6;
    const int wm     = wid >> 2;       // 0..1
    const int wn     = wid & 3;        // 0..3
    const int lane15 = lane & 15;
    const int lanehi = lane >> 4;

    f4_t acc[6] = {};

#pragma unroll
    for (int kk32 = 0; kk32 < 4; ++kk32) {
        bf8_t ah, al;
        {
            int row = wm * 16 + lane15;
            int byteoff = ((row * 128 + kk32 * 32 + lanehi * 8) * 2) ^ ((row & 7) << 4);
            ah = *(const bf8_t*)(asb[0] + byteoff);
            al = *(const bf8_t*)(asb[1] + byteoff);
        }
#pragma unroll
        for (int nf = 0; nf < 6; ++nf) {
            int fidx = ((kk32 * 24 + wn * 6 + nf) * 64 + lane) * 8;
            bf8_t bhv = *(const bf8_t*)(w2h + fidx);    // lane-contiguous
            bf8_t blv = *(const bf8_t*)(w2l + fidx);
            acc[nf] = __builtin_amdgcn_mfma_f32_16x16x32_bf16(ah, bhv, acc[nf], 0, 0, 0);
            acc[nf] = __builtin_amdgcn_mfma_f32_16x16x32_bf16(al, bhv, acc[nf], 0, 0, 0);
            acc[nf] = __builtin_amdgcn_mfma_f32_16x16x32_bf16(ah, blv, acc[nf], 0, 0, 0);
        }
    }

    const int r4 = lanehi * 4;
#pragma unroll
    for (int nf = 0; nf < 6; ++nf) {
        int n = wn * 96 + nf * 16 + lane15;
        int which = n >> 7;
        int o = n & 127;
        const float* bp = which == 0 ? qb : (which == 1 ? kb : vb);
        float bias = bp[o];
        int pos = p0 + wm * 16 + r4;
#pragma unroll
        for (int r = 0; r < 4; ++r) {
            float val = acc[nf][r] + bias;
            int di = (pos + r) * CMID + o;
            if (which == 0)      qh16[di] = (_Float16)(val * 0.0625f);
            else if (which == 1) kh16[di] = (_Float16)val;
            else                 vo[di]   = val;
        }
    }
}

// ---------------------------------------------------------------------------
// Parity-tiled neighborhood attention.
// Queries with parity (rh,rw) form a 28x28 subgrid; neighborhoods are
// dilation-1 7x7 windows (start=clip(p-3,0,21)) in the subgrid. Block =
// 4x4 subgrid query tile; union neighborhood <= 10x10 positions staged in
// LDS. QK^T via mfma_f32_16x16x32_f16 (16 queries x 112 padded nbrs x 128);
// softmax = 49-lane wave butterfly; PV = wave-uniform LDS V rows.
// Grid: 2(b) x 4(parity) x 49(tiles) = 392 blocks x 256 threads.
// ---------------------------------------------------------------------------
__global__ __launch_bounds__(256) void attn_tiled(
    const _Float16* __restrict__ qh, const _Float16* __restrict__ kh,
    const float* __restrict__ v, const float* __restrict__ As,
    float* __restrict__ out)
{
    __shared__ char Kb[112 * 256];        // K tile f16, XOR-swizzled rows
    __shared__ char Vb[100 * 256];        // V tile f16, linear rows
    __shared__ char Qb[16 * 256];         // Q tile f16, XOR-swizzled rows
    __shared__ float lg[16 * 113];        // logits, stride 113 (bank spread)
    __shared__ float awv[4][64];          // per-wave softmax weights

    const int tid = threadIdx.x;
    int bid = blockIdx.x;                  // 0..391
    const int b   = bid / 196; bid %= 196;
    const int par = bid / 49;
    const int t49 = bid % 49;
    const int rh = par >> 1, rw = par & 1;
    const int p0 = (t49 / 7) * 4, q0 = (t49 % 7) * 4;

    int smh = p0 - 3; if (smh < 0) smh = 0; if (smh > 21) smh = 21;
    int smw = q0 - 3; if (smw < 0) smw = 0; if (smw > 21) smw = 21;

    const int rlo = tid >> 4;              // 0..15
    const int t16 = tid & 15;

    {   // stage Q: 16 rows, one pass
        int qi = rlo;
        int pp = p0 + (qi >> 2), qq = q0 + (qi & 3);
        int hq = rh + 2 * pp, wq = rw + 2 * qq;
        const char* src = (const char*)(qh + ((b * HH + hq) * WW + wq) * CMID);
        uint4 d = *(const uint4*)(src + t16 * 16);
        *(uint4*)(Qb + qi * 256 + ((t16 * 16) ^ ((qi & 7) << 4))) = d;
    }
    // stage K: 112 rows (valid <100; rest clamped), swizzled
    for (int r0 = 0; r0 < 112; r0 += 16) {
        int n = r0 + rlo;
        int i = n / 10, jj = n % 10;
        int ihs = smh + i; if (ihs > 27) ihs = 27;
        int iws = smw + jj; if (iws > 27) iws = 27;
        int ih = rh + 2 * ihs, iw = rw + 2 * iws;
        const char* src = (const char*)(kh + ((b * HH + ih) * WW + iw) * CMID);
        uint4 d = *(const uint4*)(src + t16 * 16);
        *(uint4*)(Kb + n * 256 + ((t16 * 16) ^ ((n & 7) << 4))) = d;
    }
    // stage V: 100 rows fp32 -> f16, linear
    for (int r0 = 0; r0 < 112; r0 += 16) {
        int n = r0 + rlo;
        if (n < 100) {
            int i = n / 10, jj = n % 10;
            int ihs = smh + i; if (ihs > 27) ihs = 27;
            int iws = smw + jj; if (iws > 27) iws = 27;
            int ih = rh + 2 * ihs, iw = rw + 2 * iws;
            const float* src = v + ((b * HH + ih) * WW + iw) * CMID + t16 * 8;
            float4 f0 = *(const float4*)(src);
            float4 f1 = *(const float4*)(src + 4);
            h8_t d;
            d[0] = (_Float16)f0.x; d[1] = (_Float16)f0.y;
            d[2] = (_Float16)f0.z; d[3] = (_Float16)f0.w;
            d[4] = (_Float16)f1.x; d[5] = (_Float16)f1.y;
            d[6] = (_Float16)f1.z; d[7] = (_Float16)f1.w;
            *(h8_t*)(Vb + n * 256 + t16 * 16) = d;
        }
    }
    __syncthreads();

    const int lane   = tid & 63;
    const int wvid   = tid >> 6;          // wave 0..3
    const int lane15 = lane & 15;
    const int lanehi = lane >> 4;

    {   // QK^T MFMA: waves 0-2 take 2 N-frags, wave 3 takes 1 (7 total)
        int nfs = wvid * 2;
        int nfe = nfs + 2; if (nfe > 7) nfe = 7;
        for (int nf = nfs; nf < nfe; ++nf) {
            f4_t acc = {};
            int n = nf * 16 + lane15;
#pragma unroll
            for (int kk = 0; kk < 4; ++kk) {
                int koff = kk * 64 + lanehi * 16;
                h8_t a  = *(const h8_t*)(Qb + lane15 * 256 + (koff ^ ((lane15 & 7) << 4)));
                h8_t bb = *(const h8_t*)(Kb + n * 256      + (koff ^ ((n & 7) << 4)));
                acc = __builtin_amdgcn_mfma_f32_16x16x32_f16(a, bb, acc, 0, 0, 0);
            }
#pragma unroll
            for (int r = 0; r < 4; ++r)
                lg[(lanehi * 4 + r) * 113 + n] = acc[r];
        }
    }
    __syncthreads();

    const int u   = lane / 7;              // neighbor row tap (lane<49)
    const int vv2 = lane % 7;              // neighbor col tap

    for (int t = 0; t < 4; ++t) {          // 4 queries per wave, serial
        int qi = wvid * 4 + t;
        int pp = p0 + (qi >> 2), qq = q0 + (qi & 3);
        int hq = rh + 2 * pp, wq = rw + 2 * qq;
        int sp = pp - 3; if (sp < 0) sp = 0; if (sp > 21) sp = 21;
        int sq = qq - 3; if (sq < 0) sq = 0; if (sq > 21) sq = 21;
        int ru = sp - smh, rc = sq - smw;  // 0..3

        float logit = -INFINITY;
        if (lane < 49) {
            int n = (ru + u) * 10 + (rc + vv2);
            logit = lg[qi * 113 + n] + As[hq * 7 + u] + As[wq * 7 + vv2];
        }
        float m = logit;
#pragma unroll
        for (int s = 32; s > 0; s >>= 1)
            m = fmaxf(m, __shfl_xor(m, s, 64));
        float e = (lane < 49) ? expf(logit - m) : 0.f;
        float ssum = e;
#pragma unroll
        for (int s = 32; s > 0; s >>= 1)
            ssum += __shfl_xor(ssum, s, 64);
        awv[wvid][lane] = e / ssum;

        // PV: lane = channel pair, wave-uniform V rows (conflict-free)
        float o0 = 0.f, o1 = 0.f;
#pragma unroll
        for (int u2 = 0; u2 < 7; ++u2) {
            int rowb = (ru + u2) * 10 + rc;
#pragma unroll
            for (int v2 = 0; v2 < 7; ++v2) {
                float a2 = awv[wvid][u2 * 7 + v2];
                unsigned pv = *(const unsigned*)(Vb + (rowb + v2) * 256 + lane * 4);
                h2_t ph = __builtin_bit_cast(h2_t, pv);
                o0 += a2 * (float)ph[0];
                o1 += a2 * (float)ph[1];
            }
        }
        int g = (b * HH + hq) * WW + wq;
        *(float2*)(out + g * CMID + lane * 2) = make_float2(o0, o1);
    }
}

// ---------------------------------------------------------------------------
extern "C" void kernel_launch(void* const* d_in, const int* in_sizes, int n_in,
                              void* d_out, int out_size, void* d_ws, size_t ws_size,
                              hipStream_t stream)
{
    const float* x  = (const float*)d_in[0];
    const float* cw = (const float*)d_in[1];
    const float* cb = (const float*)d_in[2];
    const float* qw = (const float*)d_in[3];
    const float* qb = (const float*)d_in[4];
    const float* kw = (const float*)d_in[5];
    const float* kb = (const float*)d_in[6];
    const float* vw = (const float*)d_in[7];
    const float* vb = (const float*)d_in[8];

    float* ws = (float*)d_ws;
    _Float16* qhx = (_Float16*)(ws + QH_OFF);
    _Float16* khx = (_Float16*)(ws + KH_OFF);
    float* vx = ws + V_OFF;
    float* sf = ws + SF_OFF;
    float* As = ws + AS_OFF;
    unsigned short* wfh = (unsigned short*)(ws + WFH_OFF);
    unsigned short* wfl = (unsigned short*)(ws + WFL_OFF);
    unsigned short* w2h = (unsigned short*)(ws + W2H_OFF);
    unsigned short* w2l = (unsigned short*)(ws + W2L_OFF);
    float* out = (float*)d_out;

    hipLaunchKernelGGL(prep_w, dim3(289), dim3(256), 0, stream,
                       cw, qw, kw, vw, wfh, wfl, w2h, w2l, As);
    hipLaunchKernelGGL(conv_mfma, dim3(56, 2), dim3(512), 0, stream,
                       x, wfh, wfl, cb, sf);
    hipLaunchKernelGGL(qkv_mfma, dim3(196), dim3(512), 0, stream,
                       sf, w2h, w2l, qb, kb, vb, qhx, khx, vx);
    hipLaunchKernelGGL(attn_tiled, dim3(392), dim3(256), 0, stream,
                       qhx, khx, vx, As, out);
}

// Round 9
// 117.067 us; speedup vs baseline: 1.6803x; 1.1325x over previous
//
#include <hip/hip_runtime.h>
#include <hip/hip_bf16.h>
#include <math.h>

// Problem constants (kernel_size=7, dilation=2 fixed by the bench's setup_inputs)
#define BB   2
#define HH   56
#define WW   56
#define CIN  64
#define CMID 128

typedef short bf8_t __attribute__((ext_vector_type(8)));   // 8 x bf16 (4 VGPRs)
typedef float f4_t  __attribute__((ext_vector_type(4)));   // 4 x f32 acc
typedef _Float16 h2_t __attribute__((ext_vector_type(2)));
typedef _Float16 h8_t __attribute__((ext_vector_type(8))); // 8 x f16 (4 VGPRs)

// ws layout in floats
#define QH_OFF  0                    // q f16 (pre-scaled 1/16): 802816 h = 401408 f
#define KH_OFF  401408               // k f16
#define VH_OFF  802816               // v f16
#define AS_OFF  1204224              // 56*7 table, pre-scaled by 1/16 (512 slots)
#define WFH_OFF 1204736              // conv w hi bf16 frag-major: 73728 h = 36864 f
#define WFL_OFF 1241600
#define W2H_OFF 1278464              // qkv w hi bf16 frag-major: 49152 h = 24576 f
#define W2L_OFF 1303040
// end 1327616 floats = 5.06 MiB

__device__ __forceinline__ unsigned short f2bf(float f) {
    unsigned int u = __builtin_bit_cast(unsigned int, f);
    u += 0x7fffu + ((u >> 16) & 1u);          // RTN-even
    return (unsigned short)(u >> 16);
}
__device__ __forceinline__ float bf2f(unsigned short h) {
    unsigned int u = ((unsigned int)h) << 16;
    return __builtin_bit_cast(float, u);
}

// ---------------------------------------------------------------------------
// Kernel 0: weight prep into MFMA-fragment-major order + PE table.
// B-fragment for mfma_16x16x32: lane l holds col=l&15, k=(l>>4)*8..+8.
// ---------------------------------------------------------------------------
__global__ __launch_bounds__(256) void prep_w(
    const float* __restrict__ cw, const float* __restrict__ qw,
    const float* __restrict__ kw, const float* __restrict__ vw,
    unsigned short* __restrict__ wfh, unsigned short* __restrict__ wfl,
    unsigned short* __restrict__ w2h, unsigned short* __restrict__ w2l,
    float* __restrict__ As)
{
    int idx = blockIdx.x * 256 + threadIdx.x;
    if (idx < 9 * 2 * 8 * 64 * 8) {          // conv weights, dst-major
        int j    = idx & 7;
        int lane = (idx >> 3) & 63;
        int o16  = (idx >> 9) & 7;
        int kk32 = (idx >> 12) & 1;
        int seg  = idx >> 13;                // 0..8
        int o = o16 * 16 + (lane & 15);
        int c = kk32 * 32 + (lane >> 4) * 8 + j;
        float wv = cw[(o * 64 + c) * 9 + seg];
        unsigned short hi = f2bf(wv);
        wfh[idx] = hi; wfl[idx] = f2bf(wv - bf2f(hi));
    }
    if (idx < 4 * 24 * 64 * 8) {             // qkv weights, dst-major
        int j    = idx & 7;
        int lane = (idx >> 3) & 63;
        int rest = idx >> 9;                 // 0..95
        int n16  = rest % 24;
        int kk32 = rest / 24;                // 0..3
        int n = n16 * 16 + (lane & 15);      // 0..383
        int c = kk32 * 32 + (lane >> 4) * 8 + j;
        int which = n >> 7, o = n & 127;
        const float* src = which == 0 ? qw : (which == 1 ? kw : vw);
        float wv = src[o * 128 + c];
        unsigned short hi = f2bf(wv);
        w2h[idx] = hi; w2l[idx] = f2bf(wv - bf2f(hi));
    }
    if (blockIdx.x == 288) {
        for (int t = threadIdx.x; t < 56 * 7; t += 256) {
            int i = t / 7, j = t % 7;
            int p = i >> 1;
            int start = p - 3;
            if (start < 0) start = 0;
            if (start > 21) start = 21;
            int nidx = (i & 1) + (start + j) * 2;
            float delta = (float)(i - nidx);
            float acc = 0.f;
            for (int u = 0; u < 32; ++u) {
                float d = expf(-9.210340371976184f * (float)u * 0.03125f);
                acc += cosf(delta * d);
            }
            As[t] = acc * 0.0625f;
        }
    }
}

// ---------------------------------------------------------------------------
// FUSED conv3x3 + QKV projection, double-bf16 (hi/lo) MFMA throughout.
// Block = (wtile 0/1, h, b): M=32 (28 outputs + halo), 224 blocks x 512 thr,
// 8 waves = 2(M) x 4(N). Phase 1: stage x (3x34x64, swizzled hi/lo). Phase 2:
// conv = 9 accumulated GEMMs -> acc; +bias -> sf tile in LDS (bf16 hi/lo,
// swizzled). Phase 3: QKV GEMM N=384 (q|k|v) from LDS tile, frag-major B.
// Epilogue: q,k,v -> f16 (q pre-scaled 1/16). sf never touches global.
// Boundary cols w=28..31 are computed identically by both halves (benign).
// ---------------------------------------------------------------------------
__global__ __launch_bounds__(512) void conv_qkv_mfma(
    const float* __restrict__ x,
    const unsigned short* __restrict__ wfh, const unsigned short* __restrict__ wfl,
    const float* __restrict__ cb,
    const unsigned short* __restrict__ w2h, const unsigned short* __restrict__ w2l,
    const float* __restrict__ qb, const float* __restrict__ kb,
    const float* __restrict__ vb,
    _Float16* __restrict__ qh16, _Float16* __restrict__ kh16,
    _Float16* __restrict__ vh16)
{
    __shared__ char xsb[2][3 * 34 * 64 * 2];   // 26112 B: [hi/lo][dh][row0..33][c]
    __shared__ char sfb[2][32 * 128 * 2];      // 16384 B: [hi/lo][pos][ch]
    const int wt = blockIdx.x;
    const int h  = blockIdx.y;
    const int b  = blockIdx.z;
    const int w0 = wt * 28;
    const int tid = threadIdx.x;

    // Phase 1: stage x -> LDS bf16 hi/lo (rows = input col w0-1+row, clamped)
    for (int idx = tid; idx < 3 * 64 * 34; idx += 512) {
        int dh  = idx / (64 * 34);
        int rem = idx % (64 * 34);
        int c   = rem / 34;
        int row = rem % 34;
        int y   = h + dh - 1;
        int wg  = w0 - 1 + row;
        float val = 0.f;
        if ((unsigned)y < HH && (unsigned)wg < WW)
            val = x[((b * CIN + c) * HH + y) * WW + wg];
        unsigned short hi = f2bf(val);
        unsigned short lo = f2bf(val - bf2f(hi));
        int byteoff = (((dh * 34 + row) * 64 + c) * 2) ^ ((row & 7) << 4);
        *(unsigned short*)(xsb[0] + byteoff) = hi;
        *(unsigned short*)(xsb[1] + byteoff) = lo;
    }
    __syncthreads();

    const int lane   = tid & 63;
    const int wid    = tid >> 6;
    const int wm     = wid >> 2;       // 0..1 (M half)
    const int wn     = wid & 3;        // 0..3 (N quarter)
    const int lane15 = lane & 15;
    const int lanehi = lane >> 4;

    // Phase 2: conv MFMA (9 segs x 2 kk32, hi/lo triple)
    f4_t acc[2] = {};
    for (int seg = 0; seg < 9; ++seg) {
        const int dh = seg / 3, dw = seg % 3;
#pragma unroll
        for (int kk32 = 0; kk32 < 2; ++kk32) {
            int row = wm * 16 + lane15 + dw;            // <= 33
            int byteoff = (((dh * 34 + row) * 64 + kk32 * 32 + lanehi * 8) * 2)
                          ^ ((row & 7) << 4);
            bf8_t ah = *(const bf8_t*)(xsb[0] + byteoff);
            bf8_t al = *(const bf8_t*)(xsb[1] + byteoff);
#pragma unroll
            for (int nf = 0; nf < 2; ++nf) {
                int fidx = (((seg * 2 + kk32) * 8 + (wn * 2 + nf)) * 64 + lane) * 8;
                bf8_t bh = *(const bf8_t*)(wfh + fidx);   // lane-contiguous 1KB
                bf8_t bl = *(const bf8_t*)(wfl + fidx);
                acc[nf] = __builtin_amdgcn_mfma_f32_16x16x32_bf16(ah, bh, acc[nf], 0, 0, 0);
                acc[nf] = __builtin_amdgcn_mfma_f32_16x16x32_bf16(al, bh, acc[nf], 0, 0, 0);
                acc[nf] = __builtin_amdgcn_mfma_f32_16x16x32_bf16(ah, bl, acc[nf], 0, 0, 0);
            }
        }
    }

    // conv epilogue: +bias, split hi/lo into LDS sf tile (swizzled)
#pragma unroll
    for (int nf = 0; nf < 2; ++nf) {
        int ch = wn * 32 + nf * 16 + lane15;
        float bias = cb[ch];
#pragma unroll
        for (int r = 0; r < 4; ++r) {
            int m = wm * 16 + lanehi * 4 + r;
            float val = acc[nf][r] + bias;
            unsigned short hi = f2bf(val);
            unsigned short lo = f2bf(val - bf2f(hi));
            int byteoff = ((m * 128 + ch) * 2) ^ ((m & 7) << 4);
            *(unsigned short*)(sfb[0] + byteoff) = hi;
            *(unsigned short*)(sfb[1] + byteoff) = lo;
        }
    }
    __syncthreads();

    // Phase 3: QKV GEMM from LDS tile (N=384 stacked q|k|v)
    f4_t acc2[6] = {};
#pragma unroll
    for (int kk32 = 0; kk32 < 4; ++kk32) {
        int row = wm * 16 + lane15;
        int byteoff = ((row * 128 + kk32 * 32 + lanehi * 8) * 2) ^ ((row & 7) << 4);
        bf8_t ah = *(const bf8_t*)(sfb[0] + byteoff);
        bf8_t al = *(const bf8_t*)(sfb[1] + byteoff);
#pragma unroll
        for (int nf = 0; nf < 6; ++nf) {
            int fidx = ((kk32 * 24 + wn * 6 + nf) * 64 + lane) * 8;
            bf8_t bh = *(const bf8_t*)(w2h + fidx);       // lane-contiguous 1KB
            bf8_t bl = *(const bf8_t*)(w2l + fidx);
            acc2[nf] = __builtin_amdgcn_mfma_f32_16x16x32_bf16(ah, bh, acc2[nf], 0, 0, 0);
            acc2[nf] = __builtin_amdgcn_mfma_f32_16x16x32_bf16(al, bh, acc2[nf], 0, 0, 0);
            acc2[nf] = __builtin_amdgcn_mfma_f32_16x16x32_bf16(ah, bl, acc2[nf], 0, 0, 0);
        }
    }

    // qkv epilogue: +bias, f16 stores (q pre-scaled 1/16)
#pragma unroll
    for (int nf = 0; nf < 6; ++nf) {
        int n = wn * 96 + nf * 16 + lane15;
        int which = n >> 7;
        int o = n & 127;
        const float* bp = which == 0 ? qb : (which == 1 ? kb : vb);
        float bias = bp[o];
#pragma unroll
        for (int r = 0; r < 4; ++r) {
            int m = wm * 16 + lanehi * 4 + r;
            int wpos = w0 + m;
            if (wpos < WW) {
                float val = acc2[nf][r] + bias;
                int di = ((b * HH + h) * WW + wpos) * CMID + o;
                if (which == 0)      qh16[di] = (_Float16)(val * 0.0625f);
                else if (which == 1) kh16[di] = (_Float16)val;
                else                 vh16[di] = (_Float16)val;
            }
        }
    }
}

// ---------------------------------------------------------------------------
// Parity-tiled neighborhood attention (R8 structure; V now f16 direct copy).
// Grid: 2(b) x 4(parity) x 49(tiles) = 392 blocks x 256 threads.
// ---------------------------------------------------------------------------
__global__ __launch_bounds__(256) void attn_tiled(
    const _Float16* __restrict__ qh, const _Float16* __restrict__ kh,
    const _Float16* __restrict__ vh, const float* __restrict__ As,
    float* __restrict__ out)
{
    __shared__ char Kb[112 * 256];        // K tile f16, XOR-swizzled rows
    __shared__ char Vb[100 * 256];        // V tile f16, linear rows
    __shared__ char Qb[16 * 256];         // Q tile f16, XOR-swizzled rows
    __shared__ float lg[16 * 113];        // logits, stride 113 (bank spread)
    __shared__ float awv[4][64];          // per-wave softmax weights

    const int tid = threadIdx.x;
    int bid = blockIdx.x;                  // 0..391
    const int b   = bid / 196; bid %= 196;
    const int par = bid / 49;
    const int t49 = bid % 49;
    const int rh = par >> 1, rw = par & 1;
    const int p0 = (t49 / 7) * 4, q0 = (t49 % 7) * 4;

    int smh = p0 - 3; if (smh < 0) smh = 0; if (smh > 21) smh = 21;
    int smw = q0 - 3; if (smw < 0) smw = 0; if (smw > 21) smw = 21;

    const int rlo = tid >> 4;              // 0..15
    const int t16 = tid & 15;

    {   // stage Q: 16 rows
        int qi = rlo;
        int pp = p0 + (qi >> 2), qq = q0 + (qi & 3);
        int hq = rh + 2 * pp, wq = rw + 2 * qq;
        const char* src = (const char*)(qh + ((b * HH + hq) * WW + wq) * CMID);
        uint4 d = *(const uint4*)(src + t16 * 16);
        *(uint4*)(Qb + qi * 256 + ((t16 * 16) ^ ((qi & 7) << 4))) = d;
    }
    // stage K: 112 rows (valid <100; rest clamped), swizzled
    for (int r0 = 0; r0 < 112; r0 += 16) {
        int n = r0 + rlo;
        int i = n / 10, jj = n % 10;
        int ihs = smh + i; if (ihs > 27) ihs = 27;
        int iws = smw + jj; if (iws > 27) iws = 27;
        int ih = rh + 2 * ihs, iw = rw + 2 * iws;
        const char* src = (const char*)(kh + ((b * HH + ih) * WW + iw) * CMID);
        uint4 d = *(const uint4*)(src + t16 * 16);
        *(uint4*)(Kb + n * 256 + ((t16 * 16) ^ ((n & 7) << 4))) = d;
    }
    // stage V: 100 rows, straight f16 copy, linear
    for (int r0 = 0; r0 < 112; r0 += 16) {
        int n = r0 + rlo;
        if (n < 100) {
            int i = n / 10, jj = n % 10;
            int ihs = smh + i; if (ihs > 27) ihs = 27;
            int iws = smw + jj; if (iws > 27) iws = 27;
            int ih = rh + 2 * ihs, iw = rw + 2 * iws;
            const char* src = (const char*)(vh + ((b * HH + ih) * WW + iw) * CMID);
            uint4 d = *(const uint4*)(src + t16 * 16);
            *(uint4*)(Vb + n * 256 + t16 * 16) = d;
        }
    }
    __syncthreads();

    const int lane   = tid & 63;
    const int wvid   = tid >> 6;          // wave 0..3
    const int lane15 = lane & 15;
    const int lanehi = lane >> 4;

    {   // QK^T MFMA: waves 0-2 take 2 N-frags, wave 3 takes 1 (7 total)
        int nfs = wvid * 2;
        int nfe = nfs + 2; if (nfe > 7) nfe = 7;
        for (int nf = nfs; nf < nfe; ++nf) {
            f4_t acc = {};
            int n = nf * 16 + lane15;
#pragma unroll
            for (int kk = 0; kk < 4; ++kk) {
                int koff = kk * 64 + lanehi * 16;
                h8_t a  = *(const h8_t*)(Qb + lane15 * 256 + (koff ^ ((lane15 & 7) << 4)));
                h8_t bb = *(const h8_t*)(Kb + n * 256      + (koff ^ ((n & 7) << 4)));
                acc = __builtin_amdgcn_mfma_f32_16x16x32_f16(a, bb, acc, 0, 0, 0);
            }
#pragma unroll
            for (int r = 0; r < 4; ++r)
                lg[(lanehi * 4 + r) * 113 + n] = acc[r];
        }
    }
    __syncthreads();

    const int u   = lane / 7;              // neighbor row tap (lane<49)
    const int vv2 = lane % 7;              // neighbor col tap

    for (int t = 0; t < 4; ++t) {          // 4 queries per wave, serial
        int qi = wvid * 4 + t;
        int pp = p0 + (qi >> 2), qq = q0 + (qi & 3);
        int hq = rh + 2 * pp, wq = rw + 2 * qq;
        int sp = pp - 3; if (sp < 0) sp = 0; if (sp > 21) sp = 21;
        int sq = qq - 3; if (sq < 0) sq = 0; if (sq > 21) sq = 21;
        int ru = sp - smh, rc = sq - smw;  // 0..3

        float logit = -INFINITY;
        if (lane < 49) {
            int n = (ru + u) * 10 + (rc + vv2);
            logit = lg[qi * 113 + n] + As[hq * 7 + u] + As[wq * 7 + vv2];
        }
        float m = logit;
#pragma unroll
        for (int s = 32; s > 0; s >>= 1)
            m = fmaxf(m, __shfl_xor(m, s, 64));
        float e = (lane < 49) ? expf(logit - m) : 0.f;
        float ssum = e;
#pragma unroll
        for (int s = 32; s > 0; s >>= 1)
            ssum += __shfl_xor(ssum, s, 64);
        awv[wvid][lane] = e / ssum;

        // PV: lane = channel pair, wave-uniform V rows (conflict-free)
        float o0 = 0.f, o1 = 0.f;
#pragma unroll
        for (int u2 = 0; u2 < 7; ++u2) {
            int rowb = (ru + u2) * 10 + rc;
#pragma unroll
            for (int v2 = 0; v2 < 7; ++v2) {
                float a2 = awv[wvid][u2 * 7 + v2];
                unsigned pv = *(const unsigned*)(Vb + (rowb + v2) * 256 + lane * 4);
                h2_t ph = __builtin_bit_cast(h2_t, pv);
                o0 += a2 * (float)ph[0];
                o1 += a2 * (float)ph[1];
            }
        }
        int g = (b * HH + hq) * WW + wq;
        *(float2*)(out + g * CMID + lane * 2) = make_float2(o0, o1);
    }
}

// ---------------------------------------------------------------------------
extern "C" void kernel_launch(void* const* d_in, const int* in_sizes, int n_in,
                              void* d_out, int out_size, void* d_ws, size_t ws_size,
                              hipStream_t stream)
{
    const float* x  = (const float*)d_in[0];
    const float* cw = (const float*)d_in[1];
    const float* cb = (const float*)d_in[2];
    const float* qw = (const float*)d_in[3];
    const float* qb = (const float*)d_in[4];
    const float* kw = (const float*)d_in[5];
    const float* kb = (const float*)d_in[6];
    const float* vw = (const float*)d_in[7];
    const float* vb = (const float*)d_in[8];

    float* ws = (float*)d_ws;
    _Float16* qhx = (_Float16*)(ws + QH_OFF);
    _Float16* khx = (_Float16*)(ws + KH_OFF);
    _Float16* vhx = (_Float16*)(ws + VH_OFF);
    float* As = ws + AS_OFF;
    unsigned short* wfh = (unsigned short*)(ws + WFH_OFF);
    unsigned short* wfl = (unsigned short*)(ws + WFL_OFF);
    unsigned short* w2h = (unsigned short*)(ws + W2H_OFF);
    unsigned short* w2l = (unsigned short*)(ws + W2L_OFF);
    float* out = (float*)d_out;

    hipLaunchKernelGGL(prep_w, dim3(289), dim3(256), 0, stream,
                       cw, qw, kw, vw, wfh, wfl, w2h, w2l, As);
    hipLaunchKernelGGL(conv_qkv_mfma, dim3(2, 56, 2), dim3(512), 0, stream,
                       x, wfh, wfl, cb, w2h, w2l, qb, kb, vb, qhx, khx, vhx);
    hipLaunchKernelGGL(attn_tiled, dim3(392), dim3(256), 0, stream,
                       qhx, khx, vhx, As, out);
}

// Round 10
// 116.988 us; speedup vs baseline: 1.6815x; 1.0007x over previous
//
#include <hip/hip_runtime.h>
#include <hip/hip_bf16.h>
#include <math.h>

// Problem constants (kernel_size=7, dilation=2 fixed by the bench's setup_inputs)
#define BB   2
#define HH   56
#define WW   56
#define CIN  64
#define CMID 128

typedef short bf8_t __attribute__((ext_vector_type(8)));   // 8 x bf16 (4 VGPRs)
typedef float f4_t  __attribute__((ext_vector_type(4)));   // 4 x f32 acc
typedef _Float16 h2_t __attribute__((ext_vector_type(2)));
typedef _Float16 h8_t __attribute__((ext_vector_type(8))); // 8 x f16 (4 VGPRs)

// ws layout in floats
#define QH_OFF  0                    // q f16 (pre-scaled 1/16): 802816 h = 401408 f
#define KH_OFF  401408               // k f16
#define VH_OFF  802816               // v f16
#define AS_OFF  1204224              // 56*7 table, pre-scaled by 1/16 (512 slots)
#define WFH_OFF 1204736              // conv w hi bf16 frag-major: 73728 h = 36864 f
#define WFL_OFF 1241600
#define W2H_OFF 1278464              // qkv w hi bf16 frag-major: 49152 h = 24576 f
#define W2L_OFF 1303040
// end 1327616 floats = 5.06 MiB

__device__ __forceinline__ unsigned short f2bf(float f) {
    unsigned int u = __builtin_bit_cast(unsigned int, f);
    u += 0x7fffu + ((u >> 16) & 1u);          // RTN-even
    return (unsigned short)(u >> 16);
}
__device__ __forceinline__ float bf2f(unsigned short h) {
    unsigned int u = ((unsigned int)h) << 16;
    return __builtin_bit_cast(float, u);
}

// ---------------------------------------------------------------------------
// Kernel 0: weight prep into MFMA-fragment-major order + PE table. (R9)
// ---------------------------------------------------------------------------
__global__ __launch_bounds__(256) void prep_w(
    const float* __restrict__ cw, const float* __restrict__ qw,
    const float* __restrict__ kw, const float* __restrict__ vw,
    unsigned short* __restrict__ wfh, unsigned short* __restrict__ wfl,
    unsigned short* __restrict__ w2h, unsigned short* __restrict__ w2l,
    float* __restrict__ As)
{
    int idx = blockIdx.x * 256 + threadIdx.x;
    if (idx < 9 * 2 * 8 * 64 * 8) {          // conv weights, dst-major
        int j    = idx & 7;
        int lane = (idx >> 3) & 63;
        int o16  = (idx >> 9) & 7;
        int kk32 = (idx >> 12) & 1;
        int seg  = idx >> 13;                // 0..8
        int o = o16 * 16 + (lane & 15);
        int c = kk32 * 32 + (lane >> 4) * 8 + j;
        float wv = cw[(o * 64 + c) * 9 + seg];
        unsigned short hi = f2bf(wv);
        wfh[idx] = hi; wfl[idx] = f2bf(wv - bf2f(hi));
    }
    if (idx < 4 * 24 * 64 * 8) {             // qkv weights, dst-major
        int j    = idx & 7;
        int lane = (idx >> 3) & 63;
        int rest = idx >> 9;                 // 0..95
        int n16  = rest % 24;
        int kk32 = rest / 24;                // 0..3
        int n = n16 * 16 + (lane & 15);      // 0..383
        int c = kk32 * 32 + (lane >> 4) * 8 + j;
        int which = n >> 7, o = n & 127;
        const float* src = which == 0 ? qw : (which == 1 ? kw : vw);
        float wv = src[o * 128 + c];
        unsigned short hi = f2bf(wv);
        w2h[idx] = hi; w2l[idx] = f2bf(wv - bf2f(hi));
    }
    if (blockIdx.x == 288) {
        for (int t = threadIdx.x; t < 56 * 7; t += 256) {
            int i = t / 7, j = t % 7;
            int p = i >> 1;
            int start = p - 3;
            if (start < 0) start = 0;
            if (start > 21) start = 21;
            int nidx = (i & 1) + (start + j) * 2;
            float delta = (float)(i - nidx);
            float acc = 0.f;
            for (int u = 0; u < 32; ++u) {
                float d = expf(-9.210340371976184f * (float)u * 0.03125f);
                acc += cosf(delta * d);
            }
            As[t] = acc * 0.0625f;
        }
    }
}

// ---------------------------------------------------------------------------
// FUSED conv3x3 + QKV projection, double-bf16 (hi/lo) MFMA. (unchanged R9)
// ---------------------------------------------------------------------------
__global__ __launch_bounds__(512) void conv_qkv_mfma(
    const float* __restrict__ x,
    const unsigned short* __restrict__ wfh, const unsigned short* __restrict__ wfl,
    const float* __restrict__ cb,
    const unsigned short* __restrict__ w2h, const unsigned short* __restrict__ w2l,
    const float* __restrict__ qb, const float* __restrict__ kb,
    const float* __restrict__ vb,
    _Float16* __restrict__ qh16, _Float16* __restrict__ kh16,
    _Float16* __restrict__ vh16)
{
    __shared__ char xsb[2][3 * 34 * 64 * 2];   // 26112 B: [hi/lo][dh][row0..33][c]
    __shared__ char sfb[2][32 * 128 * 2];      // 16384 B: [hi/lo][pos][ch]
    const int wt = blockIdx.x;
    const int h  = blockIdx.y;
    const int b  = blockIdx.z;
    const int w0 = wt * 28;
    const int tid = threadIdx.x;

    for (int idx = tid; idx < 3 * 64 * 34; idx += 512) {
        int dh  = idx / (64 * 34);
        int rem = idx % (64 * 34);
        int c   = rem / 34;
        int row = rem % 34;
        int y   = h + dh - 1;
        int wg  = w0 - 1 + row;
        float val = 0.f;
        if ((unsigned)y < HH && (unsigned)wg < WW)
            val = x[((b * CIN + c) * HH + y) * WW + wg];
        unsigned short hi = f2bf(val);
        unsigned short lo = f2bf(val - bf2f(hi));
        int byteoff = (((dh * 34 + row) * 64 + c) * 2) ^ ((row & 7) << 4);
        *(unsigned short*)(xsb[0] + byteoff) = hi;
        *(unsigned short*)(xsb[1] + byteoff) = lo;
    }
    __syncthreads();

    const int lane   = tid & 63;
    const int wid    = tid >> 6;
    const int wm     = wid >> 2;       // 0..1 (M half)
    const int wn     = wid & 3;        // 0..3 (N quarter)
    const int lane15 = lane & 15;
    const int lanehi = lane >> 4;

    f4_t acc[2] = {};
    for (int seg = 0; seg < 9; ++seg) {
        const int dh = seg / 3, dw = seg % 3;
#pragma unroll
        for (int kk32 = 0; kk32 < 2; ++kk32) {
            int row = wm * 16 + lane15 + dw;            // <= 33
            int byteoff = (((dh * 34 + row) * 64 + kk32 * 32 + lanehi * 8) * 2)
                          ^ ((row & 7) << 4);
            bf8_t ah = *(const bf8_t*)(xsb[0] + byteoff);
            bf8_t al = *(const bf8_t*)(xsb[1] + byteoff);
#pragma unroll
            for (int nf = 0; nf < 2; ++nf) {
                int fidx = (((seg * 2 + kk32) * 8 + (wn * 2 + nf)) * 64 + lane) * 8;
                bf8_t bh = *(const bf8_t*)(wfh + fidx);   // lane-contiguous 1KB
                bf8_t bl = *(const bf8_t*)(wfl + fidx);
                acc[nf] = __builtin_amdgcn_mfma_f32_16x16x32_bf16(ah, bh, acc[nf], 0, 0, 0);
                acc[nf] = __builtin_amdgcn_mfma_f32_16x16x32_bf16(al, bh, acc[nf], 0, 0, 0);
                acc[nf] = __builtin_amdgcn_mfma_f32_16x16x32_bf16(ah, bl, acc[nf], 0, 0, 0);
            }
        }
    }

#pragma unroll
    for (int nf = 0; nf < 2; ++nf) {
        int ch = wn * 32 + nf * 16 + lane15;
        float bias = cb[ch];
#pragma unroll
        for (int r = 0; r < 4; ++r) {
            int m = wm * 16 + lanehi * 4 + r;
            float val = acc[nf][r] + bias;
            unsigned short hi = f2bf(val);
            unsigned short lo = f2bf(val - bf2f(hi));
            int byteoff = ((m * 128 + ch) * 2) ^ ((m & 7) << 4);
            *(unsigned short*)(sfb[0] + byteoff) = hi;
            *(unsigned short*)(sfb[1] + byteoff) = lo;
        }
    }
    __syncthreads();

    f4_t acc2[6] = {};
#pragma unroll
    for (int kk32 = 0; kk32 < 4; ++kk32) {
        int row = wm * 16 + lane15;
        int byteoff = ((row * 128 + kk32 * 32 + lanehi * 8) * 2) ^ ((row & 7) << 4);
        bf8_t ah = *(const bf8_t*)(sfb[0] + byteoff);
        bf8_t al = *(const bf8_t*)(sfb[1] + byteoff);
#pragma unroll
        for (int nf = 0; nf < 6; ++nf) {
            int fidx = ((kk32 * 24 + wn * 6 + nf) * 64 + lane) * 8;
            bf8_t bh = *(const bf8_t*)(w2h + fidx);       // lane-contiguous 1KB
            bf8_t bl = *(const bf8_t*)(w2l + fidx);
            acc2[nf] = __builtin_amdgcn_mfma_f32_16x16x32_bf16(ah, bh, acc2[nf], 0, 0, 0);
            acc2[nf] = __builtin_amdgcn_mfma_f32_16x16x32_bf16(al, bh, acc2[nf], 0, 0, 0);
            acc2[nf] = __builtin_amdgcn_mfma_f32_16x16x32_bf16(ah, bl, acc2[nf], 0, 0, 0);
        }
    }

#pragma unroll
    for (int nf = 0; nf < 6; ++nf) {
        int n = wn * 96 + nf * 16 + lane15;
        int which = n >> 7;
        int o = n & 127;
        const float* bp = which == 0 ? qb : (which == 1 ? kb : vb);
        float bias = bp[o];
#pragma unroll
        for (int r = 0; r < 4; ++r) {
            int m = wm * 16 + lanehi * 4 + r;
            int wpos = w0 + m;
            if (wpos < WW) {
                float val = acc2[nf][r] + bias;
                int di = ((b * HH + h) * WW + wpos) * CMID + o;
                if (which == 0)      qh16[di] = (_Float16)(val * 0.0625f);
                else if (which == 1) kh16[di] = (_Float16)val;
                else                 vh16[di] = (_Float16)val;
            }
        }
    }
}

// ---------------------------------------------------------------------------
// Parity-tiled neighborhood attention, 33 KB LDS (4 blocks/CU).
// One 100-row buffer time-shared: K (swizzled) for QK^T, then V (linear) for
// PV. Q A-fragments gathered per-wave from global (L2-hot). Fragment cols
// n in [100,112) alias rows n-16 (finite dup; masked out of softmax).
// Grid: 392 blocks (XCD-swizzled, 392 = 8*49) x 256 threads.
// ---------------------------------------------------------------------------
__global__ __launch_bounds__(256) void attn_tiled(
    const _Float16* __restrict__ qh, const _Float16* __restrict__ kh,
    const _Float16* __restrict__ vh, const float* __restrict__ As,
    float* __restrict__ out)
{
    __shared__ char KVb[100 * 256];       // K swizzled, then V linear
    __shared__ float lg[16 * 100];        // logits [query][nbr]
    __shared__ float awv[4][64];          // per-wave softmax weights

    const int tid = threadIdx.x;
    int bid0 = blockIdx.x;                 // 0..391
    int bid = (bid0 & 7) * 49 + (bid0 >> 3);   // bijective XCD swizzle
    const int b   = bid / 196; bid %= 196;
    const int par = bid / 49;
    const int t49 = bid % 49;
    const int rh = par >> 1, rw = par & 1;
    const int p0 = (t49 / 7) * 4, q0 = (t49 % 7) * 4;

    int smh = p0 - 3; if (smh < 0) smh = 0; if (smh > 21) smh = 21;
    int smw = q0 - 3; if (smw < 0) smw = 0; if (smw > 21) smw = 21;

    const int rlo = tid >> 4;              // 0..15
    const int t16 = tid & 15;
    const int lane   = tid & 63;
    const int wvid   = tid >> 6;           // wave 0..3
    const int lane15 = lane & 15;
    const int lanehi = lane >> 4;

    // Q A-fragments from global: row = lane15 = query, k = lanehi*8 (+32*kk)
    int qp  = p0 + (lane15 >> 2), qq2 = q0 + (lane15 & 3);
    int hql = rh + 2 * qp, wql = rw + 2 * qq2;
    const _Float16* qrow = qh + ((b * HH + hql) * WW + wql) * CMID + lanehi * 8;
    h8_t a0 = *(const h8_t*)(qrow);
    h8_t a1 = *(const h8_t*)(qrow + 32);
    h8_t a2 = *(const h8_t*)(qrow + 64);
    h8_t a3 = *(const h8_t*)(qrow + 96);

    // stage K: 100 rows, XOR-swizzled
    for (int r0 = 0; r0 < 112; r0 += 16) {
        int n = r0 + rlo;
        if (n < 100) {
            int i = n / 10, jj = n % 10;
            int ihs = smh + i; if (ihs > 27) ihs = 27;
            int iws = smw + jj; if (iws > 27) iws = 27;
            int ih = rh + 2 * ihs, iw = rw + 2 * iws;
            const char* src = (const char*)(kh + ((b * HH + ih) * WW + iw) * CMID);
            uint4 d = *(const uint4*)(src + t16 * 16);
            *(uint4*)(KVb + n * 256 + ((t16 * 16) ^ ((n & 7) << 4))) = d;
        }
    }
    __syncthreads();

    {   // QK^T MFMA: waves 0-2 take 2 N-frags, wave 3 takes 1 (7 total)
        int nfs = wvid * 2;
        int nfe = nfs + 2; if (nfe > 7) nfe = 7;
        for (int nf = nfs; nf < nfe; ++nf) {
            f4_t acc = {};
            int n = nf * 16 + lane15;
            int neff = n < 100 ? n : n - 16;       // alias pad cols to real rows
            const int swz = (neff & 7) << 4;
            const char* kb0 = KVb + neff * 256;
            h8_t b0 = *(const h8_t*)(kb0 + ((lanehi * 16) ^ swz));
            h8_t b1 = *(const h8_t*)(kb0 + ((64 + lanehi * 16) ^ swz));
            h8_t b2 = *(const h8_t*)(kb0 + ((128 + lanehi * 16) ^ swz));
            h8_t b3 = *(const h8_t*)(kb0 + ((192 + lanehi * 16) ^ swz));
            acc = __builtin_amdgcn_mfma_f32_16x16x32_f16(a0, b0, acc, 0, 0, 0);
            acc = __builtin_amdgcn_mfma_f32_16x16x32_f16(a1, b1, acc, 0, 0, 0);
            acc = __builtin_amdgcn_mfma_f32_16x16x32_f16(a2, b2, acc, 0, 0, 0);
            acc = __builtin_amdgcn_mfma_f32_16x16x32_f16(a3, b3, acc, 0, 0, 0);
            if (n < 100) {
#pragma unroll
                for (int r = 0; r < 4; ++r)
                    lg[(lanehi * 4 + r) * 100 + n] = acc[r];
            }
        }
    }
    __syncthreads();   // all QK reads of KVb + lg writes complete

    // stage V: 100 rows, linear (overwrites K buffer)
    for (int r0 = 0; r0 < 112; r0 += 16) {
        int n = r0 + rlo;
        if (n < 100) {
            int i = n / 10, jj = n % 10;
            int ihs = smh + i; if (ihs > 27) ihs = 27;
            int iws = smw + jj; if (iws > 27) iws = 27;
            int ih = rh + 2 * ihs, iw = rw + 2 * iws;
            const char* src = (const char*)(vh + ((b * HH + ih) * WW + iw) * CMID);
            uint4 d = *(const uint4*)(src + t16 * 16);
            *(uint4*)(KVb + n * 256 + t16 * 16) = d;
        }
    }
    __syncthreads();

    const int u   = lane / 7;              // neighbor row tap (lane<49)
    const int vv2 = lane % 7;              // neighbor col tap

    for (int t = 0; t < 4; ++t) {          // 4 queries per wave, serial
        int qi = wvid * 4 + t;
        int pp = p0 + (qi >> 2), qq = q0 + (qi & 3);
        int hq = rh + 2 * pp, wq = rw + 2 * qq;
        int sp = pp - 3; if (sp < 0) sp = 0; if (sp > 21) sp = 21;
        int sq = qq - 3; if (sq < 0) sq = 0; if (sq > 21) sq = 21;
        int ru = sp - smh, rc = sq - smw;  // 0..3

        float logit = -INFINITY;
        if (lane < 49) {
            int n = (ru + u) * 10 + (rc + vv2);
            logit = lg[qi * 100 + n] + As[hq * 7 + u] + As[wq * 7 + vv2];
        }
        float m = logit;
#pragma unroll
        for (int s = 32; s > 0; s >>= 1)
            m = fmaxf(m, __shfl_xor(m, s, 64));
        float e = (lane < 49) ? expf(logit - m) : 0.f;
        float ssum = e;
#pragma unroll
        for (int s = 32; s > 0; s >>= 1)
            ssum += __shfl_xor(ssum, s, 64);
        awv[wvid][lane] = e / ssum;

        // PV: lane = channel pair, wave-uniform V rows (conflict-free)
        float o0 = 0.f, o1 = 0.f;
#pragma unroll
        for (int u2 = 0; u2 < 7; ++u2) {
            int rowb = (ru + u2) * 10 + rc;
#pragma unroll
            for (int v2 = 0; v2 < 7; ++v2) {
                float a2w = awv[wvid][u2 * 7 + v2];
                unsigned pv = *(const unsigned*)(KVb + (rowb + v2) * 256 + lane * 4);
                h2_t ph = __builtin_bit_cast(h2_t, pv);
                o0 += a2w * (float)ph[0];
                o1 += a2w * (float)ph[1];
            }
        }
        int g = (b * HH + hq) * WW + wq;
        *(float2*)(out + g * CMID + lane * 2) = make_float2(o0, o1);
    }
}

// ---------------------------------------------------------------------------
extern "C" void kernel_launch(void* const* d_in, const int* in_sizes, int n_in,
                              void* d_out, int out_size, void* d_ws, size_t ws_size,
                              hipStream_t stream)
{
    const float* x  = (const float*)d_in[0];
    const float* cw = (const float*)d_in[1];
    const float* cb = (const float*)d_in[2];
    const float* qw = (const float*)d_in[3];
    const float* qb = (const float*)d_in[4];
    const float* kw = (const float*)d_in[5];
    const float* kb = (const float*)d_in[6];
    const float* vw = (const float*)d_in[7];
    const float* vb = (const float*)d_in[8];

    float* ws = (float*)d_ws;
    _Float16* qhx = (_Float16*)(ws + QH_OFF);
    _Float16* khx = (_Float16*)(ws + KH_OFF);
    _Float16* vhx = (_Float16*)(ws + VH_OFF);
    float* As = ws + AS_OFF;
    unsigned short* wfh = (unsigned short*)(ws + WFH_OFF);
    unsigned short* wfl = (unsigned short*)(ws + WFL_OFF);
    unsigned short* w2h = (unsigned short*)(ws + W2H_OFF);
    unsigned short* w2l = (unsigned short*)(ws + W2L_OFF);
    float* out = (float*)d_out;

    hipLaunchKernelGGL(prep_w, dim3(289), dim3(256), 0, stream,
                       cw, qw, kw, vw, wfh, wfl, w2h, w2l, As);
    hipLaunchKernelGGL(conv_qkv_mfma, dim3(2, 56, 2), dim3(512), 0, stream,
                       x, wfh, wfl, cb, w2h, w2l, qb, kb, vb, qhx, khx, vhx);
    hipLaunchKernelGGL(attn_tiled, dim3(392), dim3(256), 0, stream,
                       qhx, khx, vhx, As, out);
}

// Round 11
// 109.934 us; speedup vs baseline: 1.7894x; 1.0642x over previous
//
#include <hip/hip_runtime.h>
#include <hip/hip_bf16.h>
#include <math.h>

// Problem constants (kernel_size=7, dilation=2 fixed by the bench's setup_inputs)
#define BB   2
#define HH   56
#define WW   56
#define CIN  64
#define CMID 128

typedef short bf8_t __attribute__((ext_vector_type(8)));   // 8 x bf16 (4 VGPRs)
typedef float f4_t  __attribute__((ext_vector_type(4)));   // 4 x f32 acc
typedef _Float16 h2_t __attribute__((ext_vector_type(2)));
typedef _Float16 h8_t __attribute__((ext_vector_type(8))); // 8 x f16 (4 VGPRs)

// ws layout in floats
#define QH_OFF  0                    // q f16 (pre-scaled 1/16): 802816 h = 401408 f
#define KH_OFF  401408               // k f16
#define VH_OFF  802816               // v f16
#define AS_OFF  1204224              // 56*7 table, pre-scaled by 1/16 (512 slots)
#define WFH_OFF 1204736              // conv w hi bf16 frag-major: 73728 h = 36864 f
#define WFL_OFF 1241600
#define W2H_OFF 1278464              // qkv w hi bf16 frag-major: 49152 h = 24576 f
#define W2L_OFF 1303040
// end 1327616 floats = 5.06 MiB

__device__ __forceinline__ unsigned short f2bf(float f) {
    unsigned int u = __builtin_bit_cast(unsigned int, f);
    u += 0x7fffu + ((u >> 16) & 1u);          // RTN-even
    return (unsigned short)(u >> 16);
}
__device__ __forceinline__ float bf2f(unsigned short h) {
    unsigned int u = ((unsigned int)h) << 16;
    return __builtin_bit_cast(float, u);
}

// ---------------------------------------------------------------------------
// Kernel 0: weight prep into MFMA-fragment-major order + PE table. (R9)
// ---------------------------------------------------------------------------
__global__ __launch_bounds__(256) void prep_w(
    const float* __restrict__ cw, const float* __restrict__ qw,
    const float* __restrict__ kw, const float* __restrict__ vw,
    unsigned short* __restrict__ wfh, unsigned short* __restrict__ wfl,
    unsigned short* __restrict__ w2h, unsigned short* __restrict__ w2l,
    float* __restrict__ As)
{
    int idx = blockIdx.x * 256 + threadIdx.x;
    if (idx < 9 * 2 * 8 * 64 * 8) {          // conv weights, dst-major
        int j    = idx & 7;
        int lane = (idx >> 3) & 63;
        int o16  = (idx >> 9) & 7;
        int kk32 = (idx >> 12) & 1;
        int seg  = idx >> 13;                // 0..8
        int o = o16 * 16 + (lane & 15);
        int c = kk32 * 32 + (lane >> 4) * 8 + j;
        float wv = cw[(o * 64 + c) * 9 + seg];
        unsigned short hi = f2bf(wv);
        wfh[idx] = hi; wfl[idx] = f2bf(wv - bf2f(hi));
    }
    if (idx < 4 * 24 * 64 * 8) {             // qkv weights, dst-major
        int j    = idx & 7;
        int lane = (idx >> 3) & 63;
        int rest = idx >> 9;                 // 0..95
        int n16  = rest % 24;
        int kk32 = rest / 24;                // 0..3
        int n = n16 * 16 + (lane & 15);      // 0..383
        int c = kk32 * 32 + (lane >> 4) * 8 + j;
        int which = n >> 7, o = n & 127;
        const float* src = which == 0 ? qw : (which == 1 ? kw : vw);
        float wv = src[o * 128 + c];
        unsigned short hi = f2bf(wv);
        w2h[idx] = hi; w2l[idx] = f2bf(wv - bf2f(hi));
    }
    if (blockIdx.x == 288) {
        for (int t = threadIdx.x; t < 56 * 7; t += 256) {
            int i = t / 7, j = t % 7;
            int p = i >> 1;
            int start = p - 3;
            if (start < 0) start = 0;
            if (start > 21) start = 21;
            int nidx = (i & 1) + (start + j) * 2;
            float delta = (float)(i - nidx);
            float acc = 0.f;
            for (int u = 0; u < 32; ++u) {
                float d = expf(-9.210340371976184f * (float)u * 0.03125f);
                acc += cosf(delta * d);
            }
            As[t] = acc * 0.0625f;
        }
    }
}

// ---------------------------------------------------------------------------
// FUSED conv3x3 + QKV, double-bf16 MFMA. M=16 tiles (14 outputs + halo),
// grid 4x56x2 = 448 blocks x 512 thr (8 waves, each 1 conv N-frag + 3 qkv
// N-frags). LDS 22KB -> multi-block/CU; half the per-block critical path of
// the R9 M=32 version. Overlap cols (m>=14) duplicate next tile bitwise.
// ---------------------------------------------------------------------------
__global__ __launch_bounds__(512) void conv_qkv_mfma(
    const float* __restrict__ x,
    const unsigned short* __restrict__ wfh, const unsigned short* __restrict__ wfl,
    const float* __restrict__ cb,
    const unsigned short* __restrict__ w2h, const unsigned short* __restrict__ w2l,
    const float* __restrict__ qb, const float* __restrict__ kb,
    const float* __restrict__ vb,
    _Float16* __restrict__ qh16, _Float16* __restrict__ kh16,
    _Float16* __restrict__ vh16)
{
    __shared__ char xsb[2][3 * 18 * 64 * 2];   // 13824 B: [hi/lo][dh][row0..17][c]
    __shared__ char sfb[2][16 * 128 * 2];      //  8192 B: [hi/lo][pos][ch]
    const int wt = blockIdx.x;                 // 0..3
    const int h  = blockIdx.y;
    const int b  = blockIdx.z;
    const int w0 = wt * 14;
    const int tid = threadIdx.x;

    // Phase 1: stage x -> LDS bf16 hi/lo (input cols w0-1 .. w0+16)
    for (int idx = tid; idx < 3 * 64 * 18; idx += 512) {
        int dh  = idx / (64 * 18);
        int rem = idx % (64 * 18);
        int c   = rem / 18;
        int row = rem % 18;
        int y   = h + dh - 1;
        int wg  = w0 - 1 + row;
        float val = 0.f;
        if ((unsigned)y < HH && (unsigned)wg < WW)
            val = x[((b * CIN + c) * HH + y) * WW + wg];
        unsigned short hi = f2bf(val);
        unsigned short lo = f2bf(val - bf2f(hi));
        int byteoff = (((dh * 18 + row) * 64 + c) * 2) ^ ((row & 7) << 4);
        *(unsigned short*)(xsb[0] + byteoff) = hi;
        *(unsigned short*)(xsb[1] + byteoff) = lo;
    }
    __syncthreads();

    const int lane   = tid & 63;
    const int wid    = tid >> 6;       // 0..7: conv N-frag index; qkv trio base
    const int lane15 = lane & 15;
    const int lanehi = lane >> 4;

    // Phase 2: conv MFMA (9 segs x 2 kk32, hi/lo triple), 1 N-frag per wave
    f4_t acc = {};
    for (int seg = 0; seg < 9; ++seg) {
        const int dh = seg / 3, dw = seg % 3;
#pragma unroll
        for (int kk32 = 0; kk32 < 2; ++kk32) {
            int row = lane15 + dw;                     // <= 17
            int byteoff = (((dh * 18 + row) * 64 + kk32 * 32 + lanehi * 8) * 2)
                          ^ ((row & 7) << 4);
            bf8_t ah = *(const bf8_t*)(xsb[0] + byteoff);
            bf8_t al = *(const bf8_t*)(xsb[1] + byteoff);
            int fidx = (((seg * 2 + kk32) * 8 + wid) * 64 + lane) * 8;
            bf8_t bh = *(const bf8_t*)(wfh + fidx);    // lane-contiguous 1KB
            bf8_t bl = *(const bf8_t*)(wfl + fidx);
            acc = __builtin_amdgcn_mfma_f32_16x16x32_bf16(ah, bh, acc, 0, 0, 0);
            acc = __builtin_amdgcn_mfma_f32_16x16x32_bf16(al, bh, acc, 0, 0, 0);
            acc = __builtin_amdgcn_mfma_f32_16x16x32_bf16(ah, bl, acc, 0, 0, 0);
        }
    }

    // conv epilogue: +bias, split hi/lo into LDS sf tile (swizzled)
    {
        int ch = wid * 16 + lane15;
        float bias = cb[ch];
#pragma unroll
        for (int r = 0; r < 4; ++r) {
            int m = lanehi * 4 + r;                    // 0..15
            float val = acc[r] + bias;
            unsigned short hi = f2bf(val);
            unsigned short lo = f2bf(val - bf2f(hi));
            int byteoff = ((m * 128 + ch) * 2) ^ ((m & 7) << 4);
            *(unsigned short*)(sfb[0] + byteoff) = hi;
            *(unsigned short*)(sfb[1] + byteoff) = lo;
        }
    }
    __syncthreads();

    // Phase 3: QKV GEMM from LDS tile (N=384 stacked q|k|v), 3 frags/wave
    f4_t acc2[3] = {};
#pragma unroll
    for (int kk32 = 0; kk32 < 4; ++kk32) {
        int row = lane15;
        int byteoff = ((row * 128 + kk32 * 32 + lanehi * 8) * 2) ^ ((row & 7) << 4);
        bf8_t ah = *(const bf8_t*)(sfb[0] + byteoff);
        bf8_t al = *(const bf8_t*)(sfb[1] + byteoff);
#pragma unroll
        for (int nf = 0; nf < 3; ++nf) {
            int fidx = ((kk32 * 24 + wid * 3 + nf) * 64 + lane) * 8;
            bf8_t bh = *(const bf8_t*)(w2h + fidx);    // lane-contiguous 1KB
            bf8_t bl = *(const bf8_t*)(w2l + fidx);
            acc2[nf] = __builtin_amdgcn_mfma_f32_16x16x32_bf16(ah, bh, acc2[nf], 0, 0, 0);
            acc2[nf] = __builtin_amdgcn_mfma_f32_16x16x32_bf16(al, bh, acc2[nf], 0, 0, 0);
            acc2[nf] = __builtin_amdgcn_mfma_f32_16x16x32_bf16(ah, bl, acc2[nf], 0, 0, 0);
        }
    }

    // qkv epilogue: +bias, f16 stores (q pre-scaled 1/16)
#pragma unroll
    for (int nf = 0; nf < 3; ++nf) {
        int n = wid * 48 + nf * 16 + lane15;           // 0..383
        int which = n >> 7;
        int o = n & 127;
        const float* bp = which == 0 ? qb : (which == 1 ? kb : vb);
        float bias = bp[o];
#pragma unroll
        for (int r = 0; r < 4; ++r) {
            int m = lanehi * 4 + r;
            int wpos = w0 + m;
            if (wpos < WW) {                           // m>=14 dups are bitwise-identical
                float val = acc2[nf][r] + bias;
                int di = ((b * HH + h) * WW + wpos) * CMID + o;
                if (which == 0)      qh16[di] = (_Float16)(val * 0.0625f);
                else if (which == 1) kh16[di] = (_Float16)val;
                else                 vh16[di] = (_Float16)val;
            }
        }
    }
}

// ---------------------------------------------------------------------------
// Parity-tiled neighborhood attention, 33 KB LDS. (unchanged R10)
// ---------------------------------------------------------------------------
__global__ __launch_bounds__(256) void attn_tiled(
    const _Float16* __restrict__ qh, const _Float16* __restrict__ kh,
    const _Float16* __restrict__ vh, const float* __restrict__ As,
    float* __restrict__ out)
{
    __shared__ char KVb[100 * 256];       // K swizzled, then V linear
    __shared__ float lg[16 * 100];        // logits [query][nbr]
    __shared__ float awv[4][64];          // per-wave softmax weights

    const int tid = threadIdx.x;
    int bid0 = blockIdx.x;                 // 0..391
    int bid = (bid0 & 7) * 49 + (bid0 >> 3);   // bijective XCD swizzle
    const int b   = bid / 196; bid %= 196;
    const int par = bid / 49;
    const int t49 = bid % 49;
    const int rh = par >> 1, rw = par & 1;
    const int p0 = (t49 / 7) * 4, q0 = (t49 % 7) * 4;

    int smh = p0 - 3; if (smh < 0) smh = 0; if (smh > 21) smh = 21;
    int smw = q0 - 3; if (smw < 0) smw = 0; if (smw > 21) smw = 21;

    const int rlo = tid >> 4;              // 0..15
    const int t16 = tid & 15;
    const int lane   = tid & 63;
    const int wvid   = tid >> 6;           // wave 0..3
    const int lane15 = lane & 15;
    const int lanehi = lane >> 4;

    // Q A-fragments from global: row = lane15 = query, k = lanehi*8 (+32*kk)
    int qp  = p0 + (lane15 >> 2), qq2 = q0 + (lane15 & 3);
    int hql = rh + 2 * qp, wql = rw + 2 * qq2;
    const _Float16* qrow = qh + ((b * HH + hql) * WW + wql) * CMID + lanehi * 8;
    h8_t a0 = *(const h8_t*)(qrow);
    h8_t a1 = *(const h8_t*)(qrow + 32);
    h8_t a2 = *(const h8_t*)(qrow + 64);
    h8_t a3 = *(const h8_t*)(qrow + 96);

    // stage K: 100 rows, XOR-swizzled
    for (int r0 = 0; r0 < 112; r0 += 16) {
        int n = r0 + rlo;
        if (n < 100) {
            int i = n / 10, jj = n % 10;
            int ihs = smh + i; if (ihs > 27) ihs = 27;
            int iws = smw + jj; if (iws > 27) iws = 27;
            int ih = rh + 2 * ihs, iw = rw + 2 * iws;
            const char* src = (const char*)(kh + ((b * HH + ih) * WW + iw) * CMID);
            uint4 d = *(const uint4*)(src + t16 * 16);
            *(uint4*)(KVb + n * 256 + ((t16 * 16) ^ ((n & 7) << 4))) = d;
        }
    }
    __syncthreads();

    {   // QK^T MFMA: waves 0-2 take 2 N-frags, wave 3 takes 1 (7 total)
        int nfs = wvid * 2;
        int nfe = nfs + 2; if (nfe > 7) nfe = 7;
        for (int nf = nfs; nf < nfe; ++nf) {
            f4_t acc = {};
            int n = nf * 16 + lane15;
            int neff = n < 100 ? n : n - 16;       // alias pad cols to real rows
            const int swz = (neff & 7) << 4;
            const char* kb0 = KVb + neff * 256;
            h8_t b0 = *(const h8_t*)(kb0 + ((lanehi * 16) ^ swz));
            h8_t b1 = *(const h8_t*)(kb0 + ((64 + lanehi * 16) ^ swz));
            h8_t b2 = *(const h8_t*)(kb0 + ((128 + lanehi * 16) ^ swz));
            h8_t b3 = *(const h8_t*)(kb0 + ((192 + lanehi * 16) ^ swz));
            acc = __builtin_amdgcn_mfma_f32_16x16x32_f16(a0, b0, acc, 0, 0, 0);
            acc = __builtin_amdgcn_mfma_f32_16x16x32_f16(a1, b1, acc, 0, 0, 0);
            acc = __builtin_amdgcn_mfma_f32_16x16x32_f16(a2, b2, acc, 0, 0, 0);
            acc = __builtin_amdgcn_mfma_f32_16x16x32_f16(a3, b3, acc, 0, 0, 0);
            if (n < 100) {
#pragma unroll
                for (int r = 0; r < 4; ++r)
                    lg[(lanehi * 4 + r) * 100 + n] = acc[r];
            }
        }
    }
    __syncthreads();   // all QK reads of KVb + lg writes complete

    // stage V: 100 rows, linear (overwrites K buffer)
    for (int r0 = 0; r0 < 112; r0 += 16) {
        int n = r0 + rlo;
        if (n < 100) {
            int i = n / 10, jj = n % 10;
            int ihs = smh + i; if (ihs > 27) ihs = 27;
            int iws = smw + jj; if (iws > 27) iws = 27;
            int ih = rh + 2 * ihs, iw = rw + 2 * iws;
            const char* src = (const char*)(vh + ((b * HH + ih) * WW + iw) * CMID);
            uint4 d = *(const uint4*)(src + t16 * 16);
            *(uint4*)(KVb + n * 256 + t16 * 16) = d;
        }
    }
    __syncthreads();

    const int u   = lane / 7;              // neighbor row tap (lane<49)
    const int vv2 = lane % 7;              // neighbor col tap

    for (int t = 0; t < 4; ++t) {          // 4 queries per wave, serial
        int qi = wvid * 4 + t;
        int pp = p0 + (qi >> 2), qq = q0 + (qi & 3);
        int hq = rh + 2 * pp, wq = rw + 2 * qq;
        int sp = pp - 3; if (sp < 0) sp = 0; if (sp > 21) sp = 21;
        int sq = qq - 3; if (sq < 0) sq = 0; if (sq > 21) sq = 21;
        int ru = sp - smh, rc = sq - smw;  // 0..3

        float logit = -INFINITY;
        if (lane < 49) {
            int n = (ru + u) * 10 + (rc + vv2);
            logit = lg[qi * 100 + n] + As[hq * 7 + u] + As[wq * 7 + vv2];
        }
        float m = logit;
#pragma unroll
        for (int s = 32; s > 0; s >>= 1)
            m = fmaxf(m, __shfl_xor(m, s, 64));
        float e = (lane < 49) ? expf(logit - m) : 0.f;
        float ssum = e;
#pragma unroll
        for (int s = 32; s > 0; s >>= 1)
            ssum += __shfl_xor(ssum, s, 64);
        awv[wvid][lane] = e / ssum;

        // PV: lane = channel pair, wave-uniform V rows (conflict-free)
        float o0 = 0.f, o1 = 0.f;
#pragma unroll
        for (int u2 = 0; u2 < 7; ++u2) {
            int rowb = (ru + u2) * 10 + rc;
#pragma unroll
            for (int v2 = 0; v2 < 7; ++v2) {
                float a2w = awv[wvid][u2 * 7 + v2];
                unsigned pv = *(const unsigned*)(KVb + (rowb + v2) * 256 + lane * 4);
                h2_t ph = __builtin_bit_cast(h2_t, pv);
                o0 += a2w * (float)ph[0];
                o1 += a2w * (float)ph[1];
            }
        }
        int g = (b * HH + hq) * WW + wq;
        *(float2*)(out + g * CMID + lane * 2) = make_float2(o0, o1);
    }
}

// ---------------------------------------------------------------------------
extern "C" void kernel_launch(void* const* d_in, const int* in_sizes, int n_in,
                              void* d_out, int out_size, void* d_ws, size_t ws_size,
                              hipStream_t stream)
{
    const float* x  = (const float*)d_in[0];
    const float* cw = (const float*)d_in[1];
    const float* cb = (const float*)d_in[2];
    const float* qw = (const float*)d_in[3];
    const float* qb = (const float*)d_in[4];
    const float* kw = (const float*)d_in[5];
    const float* kb = (const float*)d_in[6];
    const float* vw = (const float*)d_in[7];
    const float* vb = (const float*)d_in[8];

    float* ws = (float*)d_ws;
    _Float16* qhx = (_Float16*)(ws + QH_OFF);
    _Float16* khx = (_Float16*)(ws + KH_OFF);
    _Float16* vhx = (_Float16*)(ws + VH_OFF);
    float* As = ws + AS_OFF;
    unsigned short* wfh = (unsigned short*)(ws + WFH_OFF);
    unsigned short* wfl = (unsigned short*)(ws + WFL_OFF);
    unsigned short* w2h = (unsigned short*)(ws + W2H_OFF);
    unsigned short* w2l = (unsigned short*)(ws + W2L_OFF);
    float* out = (float*)d_out;

    hipLaunchKernelGGL(prep_w, dim3(289), dim3(256), 0, stream,
                       cw, qw, kw, vw, wfh, wfl, w2h, w2l, As);
    hipLaunchKernelGGL(conv_qkv_mfma, dim3(4, 56, 2), dim3(512), 0, stream,
                       x, wfh, wfl, cb, w2h, w2l, qb, kb, vb, qhx, khx, vhx);
    hipLaunchKernelGGL(attn_tiled, dim3(392), dim3(256), 0, stream,
                       qhx, khx, vhx, As, out);
}